// Round 5
// baseline (724.179 us; speedup 1.0000x reference)
//
#include <hip/hip_runtime.h>
#include <hip/hip_bf16.h>
#include <hip/hip_cooperative_groups.h>

namespace cg = cooperative_groups;

#define NUSERS 100000
#define NITEMS 50000
#define NEDGE  1000000
#define NBATCH 16384
#define CAP_LU 320000     // filtered like-edges of batch users; expected ~164K (2x margin)
#define EPB    2048       // edges per block in passA/passC (8 per thread)
#define NBLK_E ((NEDGE + EPB - 1) / EPB)   // 489
#define NBW    3125       // NUSERS/32 bitmask words
#define GGRID  2048       // fallback persistent grid
#define CGRID  1024       // cooperative grid cap: 256 CU x 4 blocks (256thr)

// ---- workspace layout, units of 4 bytes; total 14,770,464 units = 59.1 MB ----
#define OFF_GC     0                          // 256*3 bucket counts (zeroed)
#define OFF_GB     768
#define OFF_GCUR   1536
#define OFF_BITS   2304                       // 3136 u32 batch-membership bitmask
#define OFF_NEED   (OFF_BITS + 3136)          // NUSERS bytes = 25000 units
#define OFF_ZEND   (OFF_NEED + NUSERS / 4)    // 30,440 end of zeroed region
#define OFF_IDEG   OFF_ZEND
#define OFF_UDEG   (OFF_IDEG + NITEMS)
#define OFF_SDEG   (OFF_UDEG + NUSERS)
#define OFF_ISTART (OFF_SDEG + NUSERS)
#define OFF_USTART (OFF_ISTART + NITEMS)
#define OFF_SSTART (OFF_USTART + NUSERS)
#define OFF_UEMBH  530464                     // NUSERS*32 (bf16 uemb shadow), 128-B aligned
#define OFF_REC    (OFF_UEMBH + NUSERS * 32)  // NITEMS*64 (iembh|ri1 records)
#define OFF_SOC1   (OFF_REC + NITEMS * 64)    // NUSERS*32
#define OFF_PARTLI (OFF_SOC1 + NUSERS * 32)
#define OFF_PARTLU (OFF_PARTLI + NEDGE)
#define OFF_PARTSD (OFF_PARTLU + CAP_LU)
#define OFF_CSRLI  (OFF_PARTSD + NEDGE)
#define OFF_CSRLU  (OFF_CSRLI + NEDGE)
#define OFF_CSRSD  (OFF_CSRLU + CAP_LU)
#define WS_FLOATS  (OFF_CSRSD + NEDGE)        // 14,770,464

#define SMEM_INTS  4661                       // lc(768)+go(768)+sbits(3125)

typedef unsigned short u16;

__device__ __forceinline__ float bf2f(u16 h) {
    union { unsigned u; float f; } c; c.u = ((unsigned)h) << 16; return c.f;
}
__device__ __forceinline__ u16 f2bf(float f) {
    union { float f; unsigned u; } c; c.f = f;
    unsigned r = c.u + 0x7fffu + ((c.u >> 16) & 1u);   // RNE
    return (u16)(r >> 16);
}
__device__ __forceinline__ void acc2(unsigned w, float& a0, float& a1) {
    a0 += bf2f((u16)(w & 0xffff));
    a1 += bf2f((u16)(w >> 16));
}
__device__ __forceinline__ void acc8(uint4 w, float* a) {
    acc2(w.x, a[0], a[1]); acc2(w.y, a[2], a[3]);
    acc2(w.z, a[4], a[5]); acc2(w.w, a[6], a[7]);
}

// ================= phase device functions (grid-stride, no early returns) ====

// ---- P0: zero control region + bf16 shadows (uemb->uembh, iemb->rec lo) ----
__device__ void ph_zero_cvt(const float* __restrict__ uemb, const float* __restrict__ iemb,
                            int* __restrict__ W, u16* __restrict__ uembh,
                            u16* __restrict__ rec) {
    int tid = blockIdx.x * blockDim.x + threadIdx.x;
    int nthr = gridDim.x * blockDim.x;
    for (int k = tid; k < OFF_ZEND; k += nthr) W[k] = 0;
    const int NT = (NUSERS + NITEMS) * 16;
    for (int t = tid; t < NT; t += nthr) {
        if (t < NUSERS * 16) {
            float4 v = ((const float4*)uemb)[t];
            ushort4 o;
            o.x = f2bf(v.x); o.y = f2bf(v.y); o.z = f2bf(v.z); o.w = f2bf(v.w);
            ((ushort4*)uembh)[t] = o;
        } else {
            int t2 = t - NUSERS * 16;
            int i = t2 >> 4, c = t2 & 15;
            float4 v = ((const float4*)iemb)[t2];
            ushort4 o;
            o.x = f2bf(v.x); o.y = f2bf(v.y); o.z = f2bf(v.z); o.w = f2bf(v.w);
            ((ushort4*)rec)[i * 32 + c] = o;          // lo half of record
        }
    }
}

// ---- P1: batch membership bitmask + needed flags ----
__device__ void ph_slot(const int* __restrict__ users, unsigned* __restrict__ bits,
                        unsigned char* __restrict__ needed) {
    int tid = blockIdx.x * blockDim.x + threadIdx.x;
    int nthr = gridDim.x * blockDim.x;
    for (int b = tid; b < NBATCH; b += nthr) {
        int u = users[b];
        atomicOr(&bits[u >> 5], 1u << (u & 31));
        needed[u] = 1;
    }
}

// ---- P2: per-chunk LDS bucket histograms; membership via LDS bitmask ----
__device__ void ph_passA(int* __restrict__ smem, const int* __restrict__ lu,
                         const int* __restrict__ li, const int* __restrict__ sd,
                         const int* __restrict__ ss, const unsigned* __restrict__ bits,
                         int* __restrict__ gcnt, unsigned char* __restrict__ needed) {
    int t = threadIdx.x;
    int* lc = smem;
    unsigned* sbits = (unsigned*)(smem + 768);
    for (int k = t; k < NBW; k += 256) sbits[k] = bits[k];
    for (int vb = blockIdx.x; vb < NBLK_E; vb += gridDim.x) {
        for (int k = t; k < 768; k += 256) lc[k] = 0;
        __syncthreads();
        int base = vb * EPB;
        int end = base + EPB; if (end > NEDGE) end = NEDGE;
        for (int e = base + t; e < end; e += 256) {
            int item = li[e], a = lu[e], d = sd[e];
            atomicAdd(&lc[item >> 9], 1);                        // list0: by item
            if ((sbits[a >> 5] >> (a & 31)) & 1)                 // list1: batch users
                atomicAdd(&lc[256 + (a >> 9)], 1);
            atomicAdd(&lc[512 + (d >> 9)], 1);                   // list2: by dst user
            if ((sbits[d >> 5] >> (d & 31)) & 1)                 // soc1 needed at src
                needed[ss[e]] = 1;
        }
        __syncthreads();
        for (int k = t; k < 768; k += 256)
            if (lc[k]) atomicAdd(&gcnt[k], lc[k]);
        __syncthreads();
    }
}

// ---- P3: one virtual block; 3 exclusive scans of 256 bucket counts ----
__device__ void ph_passB(const int* __restrict__ gcnt, int* __restrict__ gbase,
                         int* __restrict__ gcur, int* __restrict__ smem) {
    if (blockIdx.x != 0) return;   // safe: no grid.sync inside phases
    int* s = smem;
    int t = threadIdx.x;
    for (int j = 0; j < 3; ++j) {
        int v = gcnt[j * 256 + t];
        s[t] = v;
        __syncthreads();
        for (int o = 1; o < 256; o <<= 1) {
            int x = (t >= o) ? s[t - o] : 0;
            __syncthreads();
            s[t] += x;
            __syncthreads();
        }
        int ex = s[t] - v;
        gbase[j * 256 + t] = ex;
        gcur[j * 256 + t] = ex;
        __syncthreads();
    }
}

// ---- P4: partition edges into per-bucket chunks ----
__device__ void ph_passC(int* __restrict__ smem, const int* __restrict__ lu,
                         const int* __restrict__ li, const int* __restrict__ sd,
                         const int* __restrict__ ss, const unsigned* __restrict__ bits,
                         int* __restrict__ gcur, int* __restrict__ partLI,
                         int* __restrict__ partLU, int* __restrict__ partSD) {
    int t = threadIdx.x;
    int* lc = smem;
    int* go = smem + 768;
    unsigned* sbits = (unsigned*)(smem + 1536);
    for (int k = t; k < NBW; k += 256) sbits[k] = bits[k];
    for (int vb = blockIdx.x; vb < NBLK_E; vb += gridDim.x) {
        for (int k = t; k < 768; k += 256) lc[k] = 0;
        __syncthreads();
        int base = vb * EPB;
        int end = base + EPB; if (end > NEDGE) end = NEDGE;
        unsigned mask = 0;
        int i = 0;
        for (int e = base + t; e < end; e += 256, ++i) {
            int item = li[e], a = lu[e], d = sd[e];
            atomicAdd(&lc[item >> 9], 1);
            if ((sbits[a >> 5] >> (a & 31)) & 1) {
                atomicAdd(&lc[256 + (a >> 9)], 1);
                mask |= (1u << i);
            }
            atomicAdd(&lc[512 + (d >> 9)], 1);
        }
        __syncthreads();
        for (int k = t; k < 768; k += 256) {
            go[k] = lc[k] ? atomicAdd(&gcur[k], lc[k]) : 0;
            lc[k] = 0;
        }
        __syncthreads();
        i = 0;
        for (int e = base + t; e < end; e += 256, ++i) {
            int item = li[e], a = lu[e], d = sd[e], s_ = ss[e];
            int b0 = item >> 9;
            int r0 = atomicAdd(&lc[b0], 1);
            partLI[go[b0] + r0] = (a << 9) | (item & 511);
            if (mask & (1u << i)) {
                int b1 = 256 + (a >> 9);
                int r1 = atomicAdd(&lc[b1], 1);
                partLU[go[b1] + r1] = (item << 9) | (a & 511);
            }
            int b2 = 512 + (d >> 9);
            int r2 = atomicAdd(&lc[b2], 1);
            partSD[go[b2] + r2] = (s_ << 9) | (d & 511);
        }
        __syncthreads();
    }
}

// ---- P5: per bucket count/scan -> deg/start + rank-scatter ----
__device__ void ph_passD(int* __restrict__ smem, const int* __restrict__ gcnt,
                         const int* __restrict__ gbase, const int* __restrict__ partLI,
                         const int* __restrict__ partLU, const int* __restrict__ partSD,
                         int* __restrict__ csrli, int* __restrict__ csrlu,
                         int* __restrict__ csrsd, int* __restrict__ ideg,
                         int* __restrict__ udeg, int* __restrict__ sdeg,
                         int* __restrict__ istart, int* __restrict__ ustart,
                         int* __restrict__ sstart) {
    int t = threadIdx.x;
    int* lcnt = smem;
    int* lstart = smem + 512;
    for (int blk = blockIdx.x; blk < 588; blk += gridDim.x) {
        int list, b;
        const int* part; int* csr; int* deg; int* start; int n;
        if (blk < 196)      { list = 0; b = blk;       part = partLI; csr = csrli; deg = ideg; start = istart; n = NITEMS; }
        else if (blk < 392) { list = 1; b = blk - 196; part = partLU; csr = csrlu; deg = udeg; start = ustart; n = NUSERS; }
        else                { list = 2; b = blk - 392; part = partSD; csr = csrsd; deg = sdeg; start = sstart; n = NUSERS; }
        int base = gbase[list * 256 + b], cnt = gcnt[list * 256 + b];
        int node0 = b << 9;
        int M = n - node0; if (M > 512) M = 512; if (M < 0) M = 0;

        lcnt[t] = 0; lcnt[t + 256] = 0;
        __syncthreads();
        for (int i = t; i < cnt; i += 256) atomicAdd(&lcnt[part[base + i] & 511], 1);
        __syncthreads();
        int* ps = smem + 1024;
        int* pd = smem + 1536;
        ps[t] = lcnt[t]; ps[t + 256] = lcnt[t + 256];
        __syncthreads();
        for (int o = 1; o < 512; o <<= 1) {
            for (int k = t; k < 512; k += 256) {
                int v = ps[k];
                if (k >= o) v += ps[k - o];
                pd[k] = v;
            }
            __syncthreads();
            int* tmp = ps; ps = pd; pd = tmp;
        }
        for (int k = t; k < 512; k += 256) {
            int ex = ps[k] - lcnt[k];       // exclusive scan
            lstart[k] = ex;
            if (k < M) { deg[node0 + k] = lcnt[k]; start[node0 + k] = base + ex; }
        }
        __syncthreads();
        lcnt[t] = 0; lcnt[t + 256] = 0;
        __syncthreads();
        for (int i = t; i < cnt; i += 256) {
            int p = part[base + i];
            int nl = p & 511;
            int r = atomicAdd(&lcnt[nl], 1);
            csr[base + lstart[nl] + r] = p >> 9;
        }
        __syncthreads();
    }
}

// ---- gather helpers ----
__device__ __forceinline__ void item_store(int n, int dg, const float* __restrict__ iemb,
                                           u16* __restrict__ rec, int l8,
                                           const float* __restrict__ s) {
    float dgf = (float)dg;
    float inv = 1.0f / fmaxf(dgf, 1.0f);
    float sw  = 1.0f - dgf / (dgf + 1e-8f);
    float4 e0 = ((const float4*)(iemb + n * 64))[l8 * 2];
    float4 e1 = ((const float4*)(iemb + n * 64))[l8 * 2 + 1];
    uint4 o;
    o.x = (unsigned)f2bf(sw * e0.x + s[0] * inv) | ((unsigned)f2bf(sw * e0.y + s[1] * inv) << 16);
    o.y = (unsigned)f2bf(sw * e0.z + s[2] * inv) | ((unsigned)f2bf(sw * e0.w + s[3] * inv) << 16);
    o.z = (unsigned)f2bf(sw * e1.x + s[4] * inv) | ((unsigned)f2bf(sw * e1.y + s[5] * inv) << 16);
    o.w = (unsigned)f2bf(sw * e1.z + s[6] * inv) | ((unsigned)f2bf(sw * e1.w + s[7] * inv) << 16);
    ((uint4*)(rec + n * 128 + 64))[l8] = o;          // hi half of record
}
__device__ __forceinline__ void soc_store(int n, int dg, unsigned* __restrict__ soc1, int l8,
                                          const float* __restrict__ s) {
    float inv = 1.0f / fmaxf((float)dg, 1.0f);
    uint4 o;
    o.x = (unsigned)f2bf(s[0] * inv) | ((unsigned)f2bf(s[1] * inv) << 16);
    o.y = (unsigned)f2bf(s[2] * inv) | ((unsigned)f2bf(s[3] * inv) << 16);
    o.z = (unsigned)f2bf(s[4] * inv) | ((unsigned)f2bf(s[5] * inv) << 16);
    o.w = (unsigned)f2bf(s[6] * inv) | ((unsigned)f2bf(s[7] * inv) << 16);
    ((uint4*)(soc1 + n * 32))[l8] = o;
}

__device__ __forceinline__ void gather_pair(const unsigned* __restrict__ uh32,
                                            const int* __restrict__ csr,
                                            int jA, int dA, int jB, int dB,
                                            int lane, int g, int l8,
                                            float* __restrict__ aA,
                                            float* __restrict__ aB) {
    int cA = (lane < dA) ? csr[jA + lane] : 0;
    int cB = (lane < dB) ? csr[jB + lane] : 0;
    int kmA = dA < 64 ? dA : 64;
    int kmB = dB < 64 ? dB : 64;
    int clA = kmA > 0 ? kmA - 1 : 0;
    int clB = kmB > 0 ? kmB - 1 : 0;
    int km  = kmA > kmB ? kmA : kmB;
    for (int k = 0; k < km; k += 16) {
        int q0 = k + g, q1 = k + 8 + g;
        int iA0 = q0 < kmA ? q0 : clA;
        int iA1 = q1 < kmA ? q1 : clA;
        int iB0 = q0 < kmB ? q0 : clB;
        int iB1 = q1 < kmB ? q1 : clB;
        int rA0 = __shfl(cA, iA0), rA1 = __shfl(cA, iA1);
        int rB0 = __shfl(cB, iB0), rB1 = __shfl(cB, iB1);
        uint4 wA0 = *(const uint4*)(uh32 + rA0 * 32 + l8 * 4);
        uint4 wA1 = *(const uint4*)(uh32 + rA1 * 32 + l8 * 4);
        uint4 wB0 = *(const uint4*)(uh32 + rB0 * 32 + l8 * 4);
        uint4 wB1 = *(const uint4*)(uh32 + rB1 * 32 + l8 * 4);
        if (q0 < kmA) acc8(wA0, aA);
        if (q1 < kmA) acc8(wA1, aA);
        if (q0 < kmB) acc8(wB0, aB);
        if (q1 < kmB) acc8(wB1, aB);
    }
    for (int k = 64; k < dA; k += 8) {        // deg>64 tail (rare)
        int q = k + g; int idx = q < dA ? q : dA - 1;
        int r = csr[jA + idx];
        uint4 w = *(const uint4*)(uh32 + r * 32 + l8 * 4);
        if (q < dA) acc8(w, aA);
    }
    for (int k = 64; k < dB; k += 8) {
        int q = k + g; int idx = q < dB ? q : dB - 1;
        int r = csr[jB + idx];
        uint4 w = *(const uint4*)(uh32 + r * 32 + l8 * 4);
        if (q < dB) acc8(w, aB);
    }
    #pragma unroll
    for (int off = 8; off <= 32; off <<= 1) {
        #pragma unroll
        for (int m = 0; m < 8; ++m) {
            aA[m] += __shfl_xor(aA[m], off);
            aB[m] += __shfl_xor(aB[m], off);
        }
    }
}

// ---- P6: fused item (rec hi) + social (soc1) gathers ----
__device__ void ph_gather(const float* __restrict__ iemb, const unsigned* __restrict__ uh32,
                          const int* __restrict__ csrli, const int* __restrict__ istart,
                          const int* __restrict__ ideg, u16* __restrict__ rec,
                          const int* __restrict__ csrsd, const int* __restrict__ sstart,
                          const int* __restrict__ sdeg,
                          const unsigned char* __restrict__ needed,
                          unsigned* __restrict__ soc1) {
    int lane = threadIdx.x & 63;
    int wid  = blockIdx.x * 4 + (threadIdx.x >> 6);
    int nw   = gridDim.x * 4;
    int g = lane >> 3, l8 = lane & 7;
    const int NPI = NITEMS / 2;               // 25000 item pairs
    const int NP  = NPI + NUSERS / 2;         // + 50000 soc pairs
    for (int w = wid; w < NP; w += nw) {
        if (w < NPI) {
            int nA = w * 2, nB = nA + 1;
            int jA = istart[nA], dA = ideg[nA];
            int jB = istart[nB], dB = ideg[nB];
            float aA[8] = {0.f,0.f,0.f,0.f,0.f,0.f,0.f,0.f};
            float aB[8] = {0.f,0.f,0.f,0.f,0.f,0.f,0.f,0.f};
            gather_pair(uh32, csrli, jA, dA, jB, dB, lane, g, l8, aA, aB);
            if (g == 0)      item_store(nA, dA, iemb, rec, l8, aA);
            else if (g == 1) item_store(nB, dB, iemb, rec, l8, aB);
        } else {
            int nA = (w - NPI) * 2, nB = nA + 1;
            unsigned short nd = *(const unsigned short*)(needed + nA);   // nA even
            if (!nd) continue;
            int needA = nd & 0xff, needB = nd >> 8;
            int jA = sstart[nA], dA = needA ? sdeg[nA] : 0;
            int jB = sstart[nB], dB = needB ? sdeg[nB] : 0;
            float aA[8] = {0.f,0.f,0.f,0.f,0.f,0.f,0.f,0.f};
            float aB[8] = {0.f,0.f,0.f,0.f,0.f,0.f,0.f,0.f};
            gather_pair(uh32, csrsd, jA, dA, jB, dB, lane, g, l8, aA, aB);
            if (g == 0 && needA)      soc_store(nA, dA, soc1, l8, aA);
            else if (g == 1 && needB) soc_store(nB, dB, soc1, l8, aB);
        }
    }
}

// ---- P7: fused epilogue, TWO batch elements per wave ----
__device__ void ph_final(const int* __restrict__ users, const int* __restrict__ items,
                         const float* __restrict__ uemb, const float* __restrict__ iemb,
                         const u16* __restrict__ rec, const int* __restrict__ csrlu,
                         const int* __restrict__ ustart, const int* __restrict__ udeg,
                         const u16* __restrict__ soc1, const int* __restrict__ csrsd,
                         const int* __restrict__ sstart, const int* __restrict__ sdeg,
                         float* __restrict__ out) {
    int d    = threadIdx.x & 63;
    int wid0 = blockIdx.x * 4 + (threadIdx.x >> 6);
    int nw   = gridDim.x * 4;
    for (int wid = wid0; wid < NBATCH / 2; wid += nw) {
        int bA = wid, bB = wid + NBATCH / 2;
        int uA = users[bA], uB = users[bB];
        int itA = items[bA], itB = items[bB];
        int juA = ustart[uA], duA = udeg[uA];
        int juB = ustart[uB], duB = udeg[uB];
        int jsA = sstart[uA], dsA = sdeg[uA];
        int jsB = sstart[uB], dsB = sdeg[uB];
        int cvUA = (d < duA) ? csrlu[juA + d] : 0;
        int cvUB = (d < duB) ? csrlu[juB + d] : 0;
        int cvSA = (d < dsA) ? csrsd[jsA + d] : 0;
        int cvSB = (d < dsB) ? csrsd[jsB + d] : 0;
        int kmuA = duA < 64 ? duA : 64, cluA = kmuA > 0 ? kmuA - 1 : 0;
        int kmuB = duB < 64 ? duB : 64, cluB = kmuB > 0 ? kmuB - 1 : 0;
        int kmu = kmuA > kmuB ? kmuA : kmuB;
        float pA0=0.f,pA1=0.f,pA2=0.f,pA3=0.f, qA0=0.f,qA1=0.f,qA2=0.f,qA3=0.f;
        float pB0=0.f,pB1=0.f,pB2=0.f,pB3=0.f, qB0=0.f,qB1=0.f,qB2=0.f,qB3=0.f;
        for (int k = 0; k < kmu; k += 4) {
            int xA0 = k   < kmuA ? k   : cluA, xA1 = k+1 < kmuA ? k+1 : cluA;
            int xA2 = k+2 < kmuA ? k+2 : cluA, xA3 = k+3 < kmuA ? k+3 : cluA;
            int xB0 = k   < kmuB ? k   : cluB, xB1 = k+1 < kmuB ? k+1 : cluB;
            int xB2 = k+2 < kmuB ? k+2 : cluB, xB3 = k+3 < kmuB ? k+3 : cluB;
            int iA0 = __shfl(cvUA, xA0), iA1 = __shfl(cvUA, xA1);
            int iA2 = __shfl(cvUA, xA2), iA3 = __shfl(cvUA, xA3);
            int iB0 = __shfl(cvUB, xB0), iB1 = __shfl(cvUB, xB1);
            int iB2 = __shfl(cvUB, xB2), iB3 = __shfl(cvUB, xB3);
            float tA0 = bf2f(rec[iA0*128 + d]),      tA1 = bf2f(rec[iA1*128 + d]);
            float tA2 = bf2f(rec[iA2*128 + d]),      tA3 = bf2f(rec[iA3*128 + d]);
            float rA0 = bf2f(rec[iA0*128 + 64 + d]), rA1 = bf2f(rec[iA1*128 + 64 + d]);
            float rA2 = bf2f(rec[iA2*128 + 64 + d]), rA3 = bf2f(rec[iA3*128 + 64 + d]);
            float tB0 = bf2f(rec[iB0*128 + d]),      tB1 = bf2f(rec[iB1*128 + d]);
            float tB2 = bf2f(rec[iB2*128 + d]),      tB3 = bf2f(rec[iB3*128 + d]);
            float rB0 = bf2f(rec[iB0*128 + 64 + d]), rB1 = bf2f(rec[iB1*128 + 64 + d]);
            float rB2 = bf2f(rec[iB2*128 + 64 + d]), rB3 = bf2f(rec[iB3*128 + 64 + d]);
            if (k   < kmuA) { pA0 += tA0; qA0 += rA0; }
            if (k+1 < kmuA) { pA1 += tA1; qA1 += rA1; }
            if (k+2 < kmuA) { pA2 += tA2; qA2 += rA2; }
            if (k+3 < kmuA) { pA3 += tA3; qA3 += rA3; }
            if (k   < kmuB) { pB0 += tB0; qB0 += rB0; }
            if (k+1 < kmuB) { pB1 += tB1; qB1 += rB1; }
            if (k+2 < kmuB) { pB2 += tB2; qB2 += rB2; }
            if (k+3 < kmuB) { pB3 += tB3; qB3 += rB3; }
        }
        for (int j = juA + 64; j < juA + duA; ++j) {
            int i0 = csrlu[j];
            pA0 += bf2f(rec[i0*128 + d]); qA0 += bf2f(rec[i0*128 + 64 + d]);
        }
        for (int j = juB + 64; j < juB + duB; ++j) {
            int i0 = csrlu[j];
            pB0 += bf2f(rec[i0*128 + d]); qB0 += bf2f(rec[i0*128 + 64 + d]);
        }
        int kmsA = dsA < 64 ? dsA : 64, clsA = kmsA > 0 ? kmsA - 1 : 0;
        int kmsB = dsB < 64 ? dsB : 64, clsB = kmsB > 0 ? kmsB - 1 : 0;
        int kms = kmsA > kmsB ? kmsA : kmsB;
        float sA0=0.f,sA1=0.f,sA2=0.f,sA3=0.f, sB0=0.f,sB1=0.f,sB2=0.f,sB3=0.f;
        for (int k = 0; k < kms; k += 4) {
            int xA0 = k   < kmsA ? k   : clsA, xA1 = k+1 < kmsA ? k+1 : clsA;
            int xA2 = k+2 < kmsA ? k+2 : clsA, xA3 = k+3 < kmsA ? k+3 : clsA;
            int xB0 = k   < kmsB ? k   : clsB, xB1 = k+1 < kmsB ? k+1 : clsB;
            int xB2 = k+2 < kmsB ? k+2 : clsB, xB3 = k+3 < kmsB ? k+3 : clsB;
            int cA0 = __shfl(cvSA, xA0), cA1 = __shfl(cvSA, xA1);
            int cA2 = __shfl(cvSA, xA2), cA3 = __shfl(cvSA, xA3);
            int cB0 = __shfl(cvSB, xB0), cB1 = __shfl(cvSB, xB1);
            int cB2 = __shfl(cvSB, xB2), cB3 = __shfl(cvSB, xB3);
            float fA0 = bf2f(soc1[cA0*64 + d]), fA1 = bf2f(soc1[cA1*64 + d]);
            float fA2 = bf2f(soc1[cA2*64 + d]), fA3 = bf2f(soc1[cA3*64 + d]);
            float fB0 = bf2f(soc1[cB0*64 + d]), fB1 = bf2f(soc1[cB1*64 + d]);
            float fB2 = bf2f(soc1[cB2*64 + d]), fB3 = bf2f(soc1[cB3*64 + d]);
            if (k   < kmsA) sA0 += fA0;
            if (k+1 < kmsA) sA1 += fA1;
            if (k+2 < kmsA) sA2 += fA2;
            if (k+3 < kmsA) sA3 += fA3;
            if (k   < kmsB) sB0 += fB0;
            if (k+1 < kmsB) sB1 += fB1;
            if (k+2 < kmsB) sB2 += fB2;
            if (k+3 < kmsB) sB3 += fB3;
        }
        for (int j = jsA + 64; j < jsA + dsA; ++j)
            sA0 += bf2f(soc1[csrsd[j]*64 + d]);
        for (int j = jsB + 64; j < jsB + dsB; ++j)
            sB0 += bf2f(soc1[csrsd[j]*64 + d]);
        {
            float invU = 1.0f / fmaxf((float)duA, 1.0f);
            float ru1 = ((pA0 + pA1) + (pA2 + pA3)) * invU;
            float ru2 = ((qA0 + qA1) + (qA2 + qA3)) * invU;
            float s2 = ((sA0 + sA1) + (sA2 + sA3)) / fmaxf((float)dsA, 1.0f);
            float ud = (float)duA;
            float usw = 1.0f - ud / (ud + 1e-8f);
            float ue = uemb[uA * 64 + d];
            float s1 = bf2f(soc1[uA * 64 + d]);
            float r1 = usw * ue + ru1;
            float r2 = usw * r1 + ru2;
            float fu = ue + 0.5f * (s1 + r1) + 0.5f * (s2 + r2);
            float iv = iemb[itA * 64 + d];
            out[NBATCH + bA * 64 + d]               = fu;
            out[NBATCH + NBATCH * 64 + bA * 64 + d] = iv;
            float p = fu * iv;
            #pragma unroll
            for (int o = 32; o > 0; o >>= 1) p += __shfl_down(p, o);
            if (d == 0) out[bA] = 1.0f / (1.0f + __expf(-p));
        }
        {
            float invU = 1.0f / fmaxf((float)duB, 1.0f);
            float ru1 = ((pB0 + pB1) + (pB2 + pB3)) * invU;
            float ru2 = ((qB0 + qB1) + (qB2 + qB3)) * invU;
            float s2 = ((sB0 + sB1) + (sB2 + sB3)) / fmaxf((float)dsB, 1.0f);
            float ud = (float)duB;
            float usw = 1.0f - ud / (ud + 1e-8f);
            float ue = uemb[uB * 64 + d];
            float s1 = bf2f(soc1[uB * 64 + d]);
            float r1 = usw * ue + ru1;
            float r2 = usw * r1 + ru2;
            float fu = ue + 0.5f * (s1 + r1) + 0.5f * (s2 + r2);
            float iv = iemb[itB * 64 + d];
            out[NBATCH + bB * 64 + d]               = fu;
            out[NBATCH + NBATCH * 64 + bB * 64 + d] = iv;
            float p = fu * iv;
            #pragma unroll
            for (int o = 32; o > 0; o >>= 1) p += __shfl_down(p, o);
            if (d == 0) out[bB] = 1.0f / (1.0f + __expf(-p));
        }
    }
}

// ================= cooperative mega-kernel (1 dispatch, 7 grid syncs) ========
__global__ void __launch_bounds__(256, 4)
k_mega(const float* uemb, const float* iemb, const int* users, const int* items,
       const int* ssrc, const int* sdst, const int* lu, const int* li,
       int* W, float* out) {
    __shared__ int smem[SMEM_INTS];
    cg::grid_group grid = cg::this_grid();

    int*           gcnt   = W + OFF_GC;
    int*           gbase  = W + OFF_GB;
    int*           gcur   = W + OFF_GCUR;
    unsigned*      bits   = (unsigned*)(W + OFF_BITS);
    unsigned char* needed = (unsigned char*)(W + OFF_NEED);
    int*           ideg   = W + OFF_IDEG;
    int*           udeg   = W + OFF_UDEG;
    int*           sdeg   = W + OFF_SDEG;
    int*           istart = W + OFF_ISTART;
    int*           ustart = W + OFF_USTART;
    int*           sstart = W + OFF_SSTART;
    u16*           uembh  = (u16*)(W + OFF_UEMBH);
    u16*           rec    = (u16*)(W + OFF_REC);
    u16*           soc1   = (u16*)(W + OFF_SOC1);
    int*           partLI = W + OFF_PARTLI;
    int*           partLU = W + OFF_PARTLU;
    int*           partSD = W + OFF_PARTSD;
    int*           csrli  = W + OFF_CSRLI;
    int*           csrlu  = W + OFF_CSRLU;
    int*           csrsd  = W + OFF_CSRSD;

    ph_zero_cvt(uemb, iemb, W, uembh, rec);
    grid.sync();
    ph_slot(users, bits, needed);
    grid.sync();
    ph_passA(smem, lu, li, sdst, ssrc, bits, gcnt, needed);
    grid.sync();
    ph_passB(gcnt, gbase, gcur, smem);
    grid.sync();
    ph_passC(smem, lu, li, sdst, ssrc, bits, gcur, partLI, partLU, partSD);
    grid.sync();
    ph_passD(smem, gcnt, gbase, partLI, partLU, partSD, csrli, csrlu, csrsd,
             ideg, udeg, sdeg, istart, ustart, sstart);
    grid.sync();
    ph_gather(iemb, (const unsigned*)uembh, csrli, istart, ideg, rec,
              csrsd, sstart, sdeg, needed, soc1 ? (unsigned*)soc1 : nullptr);
    grid.sync();
    ph_final(users, items, uemb, iemb, rec, csrlu, ustart, udeg,
             soc1, csrsd, sstart, sdeg, out);
}

// ================= fallback wrappers (proven 8-dispatch path) ================
__global__ void __launch_bounds__(256) k_f_zero(const float* uemb, const float* iemb, int* W) {
    ph_zero_cvt(uemb, iemb, W, (u16*)(W + OFF_UEMBH), (u16*)(W + OFF_REC));
}
__global__ void __launch_bounds__(256) k_f_slot(const int* users, int* W) {
    ph_slot(users, (unsigned*)(W + OFF_BITS), (unsigned char*)(W + OFF_NEED));
}
__global__ void __launch_bounds__(256) k_f_passA(const int* lu, const int* li,
                                                 const int* sd, const int* ss, int* W) {
    __shared__ int smem[SMEM_INTS];
    ph_passA(smem, lu, li, sd, ss, (unsigned*)(W + OFF_BITS), W + OFF_GC,
             (unsigned char*)(W + OFF_NEED));
}
__global__ void __launch_bounds__(256) k_f_passB(int* W) {
    __shared__ int smem[256];
    ph_passB(W + OFF_GC, W + OFF_GB, W + OFF_GCUR, smem);
}
__global__ void __launch_bounds__(256) k_f_passC(const int* lu, const int* li,
                                                 const int* sd, const int* ss, int* W) {
    __shared__ int smem[SMEM_INTS];
    ph_passC(smem, lu, li, sd, ss, (unsigned*)(W + OFF_BITS), W + OFF_GCUR,
             W + OFF_PARTLI, W + OFF_PARTLU, W + OFF_PARTSD);
}
__global__ void __launch_bounds__(256) k_f_passD(int* W) {
    __shared__ int smem[SMEM_INTS];
    ph_passD(smem, W + OFF_GC, W + OFF_GB, W + OFF_PARTLI, W + OFF_PARTLU,
             W + OFF_PARTSD, W + OFF_CSRLI, W + OFF_CSRLU, W + OFF_CSRSD,
             W + OFF_IDEG, W + OFF_UDEG, W + OFF_SDEG,
             W + OFF_ISTART, W + OFF_USTART, W + OFF_SSTART);
}
__global__ void __launch_bounds__(256) k_f_gather(const float* iemb, int* W) {
    ph_gather(iemb, (const unsigned*)(W + OFF_UEMBH), W + OFF_CSRLI, W + OFF_ISTART,
              W + OFF_IDEG, (u16*)(W + OFF_REC), W + OFF_CSRSD, W + OFF_SSTART,
              W + OFF_SDEG, (unsigned char*)(W + OFF_NEED), (unsigned*)(W + OFF_SOC1));
}
__global__ void __launch_bounds__(256) k_f_final(const int* users, const int* items,
                                                 const float* uemb, const float* iemb,
                                                 int* W, float* out) {
    ph_final(users, items, uemb, iemb, (const u16*)(W + OFF_REC), W + OFF_CSRLU,
             W + OFF_USTART, W + OFF_UDEG, (const u16*)(W + OFF_SOC1), W + OFF_CSRSD,
             W + OFF_SSTART, W + OFF_SDEG, out);
}

extern "C" void kernel_launch(void* const* d_in, const int* in_sizes, int n_in,
                              void* d_out, int out_size, void* d_ws, size_t ws_size,
                              hipStream_t stream) {
    const float* uemb  = (const float*)d_in[0];
    const float* iemb  = (const float*)d_in[1];
    const int*   users = (const int*)d_in[2];
    const int*   items = (const int*)d_in[3];
    const int*   ssrc  = (const int*)d_in[4];
    const int*   sdst  = (const int*)d_in[5];
    const int*   lu    = (const int*)d_in[6];
    const int*   li    = (const int*)d_in[7];
    float* out = (float*)d_out;

    if (ws_size < (size_t)WS_FLOATS * 4) return;  // would show absmax==0.5 diagnostic

    int* W = (int*)d_ws;

    // one-time probe: cooperative support + co-resident grid size (host query, no stream ops)
    static int coop_grid = -2;
    if (coop_grid == -2) {
        int dev = 0;
        hipDeviceProp_t prop;
        int nb = 0;
        if (hipGetDevice(&dev) == hipSuccess &&
            hipGetDeviceProperties(&prop, dev) == hipSuccess &&
            prop.cooperativeLaunch &&
            hipOccupancyMaxActiveBlocksPerMultiprocessor(&nb, k_mega, 256, 0) == hipSuccess &&
            nb > 0) {
            long g = (long)nb * prop.multiProcessorCount;
            coop_grid = (int)(g < CGRID ? g : CGRID);
        } else {
            coop_grid = -1;
        }
        (void)hipGetLastError();
    }

    if (coop_grid > 0) {
        const float* a0 = uemb; const float* a1 = iemb;
        const int* a2 = users; const int* a3 = items;
        const int* a4 = ssrc;  const int* a5 = sdst;
        const int* a6 = lu;    const int* a7 = li;
        int* a8 = W; float* a9 = out;
        void* args[] = { &a0, &a1, &a2, &a3, &a4, &a5, &a6, &a7, &a8, &a9 };
        hipError_t e = hipLaunchCooperativeKernel(k_mega, dim3(coop_grid), dim3(256),
                                                  args, 0, stream);
        if (e == hipSuccess) return;
        (void)hipGetLastError();   // clear, fall through to multi-launch path
    }

    // ---- fallback: proven multi-dispatch pipeline (identical phase code) ----
    const int B = 256;
    k_f_zero<<<2048, B, 0, stream>>>(uemb, iemb, W);
    k_f_slot<<<64, B, 0, stream>>>(users, W);
    k_f_passA<<<NBLK_E, B, 0, stream>>>(lu, li, sdst, ssrc, W);
    k_f_passB<<<1, B, 0, stream>>>(W);
    k_f_passC<<<NBLK_E, B, 0, stream>>>(lu, li, sdst, ssrc, W);
    k_f_passD<<<588, B, 0, stream>>>(W);
    k_f_gather<<<GGRID, B, 0, stream>>>(iemb, W);
    k_f_final<<<GGRID, B, 0, stream>>>(users, items, uemb, iemb, W, out);
}

// Round 6
// 258.952 us; speedup vs baseline: 2.7966x; 2.7966x over previous
//
#include <hip/hip_runtime.h>
#include <hip/hip_bf16.h>

#define NUSERS 100000
#define NITEMS 50000
#define NEDGE  1000000
#define NBATCH 16384
#define CAP_LU 320000     // filtered like-edges of batch users; expected ~164K (2x margin)
#define EPB    2048       // edges per block in passA/passC (8 per thread)
#define NBLK_E ((NEDGE + EPB - 1) / EPB)   // 489
#define NBW    3125       // NUSERS/32 bitmask words
#define GGRID  2048       // persistent grid: 256 CU x 8 blocks (256thr)
#define NB_CVT 9375       // (NUSERS+NITEMS)*16 / 256 float4-cvt blocks
#define NB_INIT (NB_CVT + (NBATCH + 255) / 256)   // + slot blocks

// ---- workspace layout, units of 4 bytes; total 14,770,464 units = 59.1 MB ----
// All bf16 row arrays (uembh / rec / soc1) are 128-B aligned.
// rec = per-item 256-B record: [128B iembh row | 128B ri1 row].
#define OFF_GC     0                          // 256*3 bucket counts (memset 0)
#define OFF_GB     768
#define OFF_GCUR   1536
#define OFF_BITS   2304                       // 3136 u32 batch-membership bitmask
#define OFF_NEED   (OFF_BITS + 3136)          // NUSERS bytes = 25000 units
#define OFF_ZEND   (OFF_NEED + NUSERS / 4)    // 30,440 end of memset-0 region
#define OFF_IDEG   OFF_ZEND
#define OFF_UDEG   (OFF_IDEG + NITEMS)
#define OFF_SDEG   (OFF_UDEG + NUSERS)
#define OFF_ISTART (OFF_SDEG + NUSERS)
#define OFF_USTART (OFF_ISTART + NITEMS)
#define OFF_SSTART (OFF_USTART + NUSERS)
#define OFF_UEMBH  530464                     // NUSERS*32 (bf16 uemb shadow), 128-B aligned
#define OFF_REC    (OFF_UEMBH + NUSERS * 32)  // NITEMS*64 (iembh|ri1 records)
#define OFF_SOC1   (OFF_REC + NITEMS * 64)    // NUSERS*32
#define OFF_PARTLI (OFF_SOC1 + NUSERS * 32)
#define OFF_PARTLU (OFF_PARTLI + NEDGE)
#define OFF_PARTSD (OFF_PARTLU + CAP_LU)
#define OFF_CSRLI  (OFF_PARTSD + NEDGE)
#define OFF_CSRLU  (OFF_CSRLI + NEDGE)
#define OFF_CSRSD  (OFF_CSRLU + CAP_LU)
#define WS_FLOATS  (OFF_CSRSD + NEDGE)        // 14,770,464

typedef unsigned short u16;

__device__ __forceinline__ float bf2f(u16 h) {
    union { unsigned u; float f; } c; c.u = ((unsigned)h) << 16; return c.f;
}
__device__ __forceinline__ u16 f2bf(float f) {
    union { float f; unsigned u; } c; c.f = f;
    unsigned r = c.u + 0x7fffu + ((c.u >> 16) & 1u);   // RNE
    return (u16)(r >> 16);
}
__device__ __forceinline__ void acc2(unsigned w, float& a0, float& a1) {
    a0 += bf2f((u16)(w & 0xffff));
    a1 += bf2f((u16)(w >> 16));
}
__device__ __forceinline__ void acc8(uint4 w, float* a) {
    acc2(w.x, a[0], a[1]); acc2(w.y, a[2], a[3]);
    acc2(w.z, a[4], a[5]); acc2(w.w, a[6], a[7]);
}

// ---- init: bf16 shadows (uemb->uembh, iemb->rec lo-half) + batch slot ----
__global__ void k_init(const float* __restrict__ uemb, const float* __restrict__ iemb,
                       const int* __restrict__ users, u16* __restrict__ uembh,
                       u16* __restrict__ rec, unsigned* __restrict__ bits,
                       unsigned char* __restrict__ needed) {
    int blk = blockIdx.x;
    if (blk < NB_CVT) {
        int t = blk * 256 + threadIdx.x;
        if (t < NUSERS * 16) {
            float4 v = ((const float4*)uemb)[t];
            ushort4 o;
            o.x = f2bf(v.x); o.y = f2bf(v.y); o.z = f2bf(v.z); o.w = f2bf(v.w);
            ((ushort4*)uembh)[t] = o;
        } else {
            int t2 = t - NUSERS * 16;                 // < NITEMS*16
            int i = t2 >> 4, c = t2 & 15;             // item, chunk of 4 dims
            float4 v = ((const float4*)iemb)[t2];
            ushort4 o;
            o.x = f2bf(v.x); o.y = f2bf(v.y); o.z = f2bf(v.z); o.w = f2bf(v.w);
            ((ushort4*)rec)[i * 32 + c] = o;          // lo half of record
        }
    } else {
        int b = (blk - NB_CVT) * 256 + threadIdx.x;
        if (b < NBATCH) {
            int u = users[b];
            atomicOr(&bits[u >> 5], 1u << (u & 31));
            needed[u] = 1;
        }
    }
}

// ---- pass A: per-block LDS bucket histograms; membership via LDS bitmask ----
__global__ void k_passA(const int* __restrict__ lu, const int* __restrict__ li,
                        const int* __restrict__ sd, const int* __restrict__ ss,
                        const unsigned* __restrict__ bits, int* __restrict__ gcnt,
                        unsigned char* __restrict__ needed) {
    __shared__ int lc[768];
    __shared__ unsigned sbits[NBW];
    int t = threadIdx.x;
    for (int k = t; k < 768; k += 256) lc[k] = 0;
    for (int k = t; k < NBW; k += 256) sbits[k] = bits[k];
    __syncthreads();
    int base = blockIdx.x * EPB;
    int end = base + EPB; if (end > NEDGE) end = NEDGE;
    for (int e = base + t; e < end; e += 256) {
        int item = li[e], a = lu[e], d = sd[e];
        atomicAdd(&lc[item >> 9], 1);                        // list0: by item
        if ((sbits[a >> 5] >> (a & 31)) & 1)                 // list1: batch users
            atomicAdd(&lc[256 + (a >> 9)], 1);
        atomicAdd(&lc[512 + (d >> 9)], 1);                   // list2: by dst user
        if ((sbits[d >> 5] >> (d & 31)) & 1)                 // soc1 needed at source
            needed[ss[e]] = 1;
    }
    __syncthreads();
    for (int k = t; k < 768; k += 256)
        if (lc[k]) atomicAdd(&gcnt[k], lc[k]);
}

// ---- pass B: one block; 3 exclusive scans of 256 bucket counts ----
__global__ void k_passB(const int* __restrict__ gcnt, int* __restrict__ gbase,
                        int* __restrict__ gcur) {
    __shared__ int s[256];
    int t = threadIdx.x;
    for (int j = 0; j < 3; ++j) {
        int v = gcnt[j * 256 + t];
        s[t] = v;
        __syncthreads();
        for (int o = 1; o < 256; o <<= 1) {
            int x = (t >= o) ? s[t - o] : 0;
            __syncthreads();
            s[t] += x;
            __syncthreads();
        }
        int ex = s[t] - v;
        gbase[j * 256 + t] = ex;
        gcur[j * 256 + t] = ex;
        __syncthreads();
    }
}

// ---- pass C: partition edges into per-bucket chunks ----
__global__ void k_passC(const int* __restrict__ lu, const int* __restrict__ li,
                        const int* __restrict__ sd, const int* __restrict__ ss,
                        const unsigned* __restrict__ bits, int* __restrict__ gcur,
                        int* __restrict__ partLI, int* __restrict__ partLU,
                        int* __restrict__ partSD) {
    __shared__ int lc[768];   // local counts, then rank counters
    __shared__ int go[768];   // this block's global chunk offsets
    __shared__ unsigned sbits[NBW];
    int t = threadIdx.x;
    for (int k = t; k < 768; k += 256) lc[k] = 0;
    for (int k = t; k < NBW; k += 256) sbits[k] = bits[k];
    __syncthreads();
    int base = blockIdx.x * EPB;
    int end = base + EPB; if (end > NEDGE) end = NEDGE;
    unsigned mask = 0;        // bit i: edge (base + i*256 + t) belongs to a batch user
    int i = 0;
    for (int e = base + t; e < end; e += 256, ++i) {
        int item = li[e], a = lu[e], d = sd[e];
        atomicAdd(&lc[item >> 9], 1);
        if ((sbits[a >> 5] >> (a & 31)) & 1) {
            atomicAdd(&lc[256 + (a >> 9)], 1);
            mask |= (1u << i);
        }
        atomicAdd(&lc[512 + (d >> 9)], 1);
    }
    __syncthreads();
    for (int k = t; k < 768; k += 256) {
        go[k] = lc[k] ? atomicAdd(&gcur[k], lc[k]) : 0;
        lc[k] = 0;
    }
    __syncthreads();
    i = 0;
    for (int e = base + t; e < end; e += 256, ++i) {
        int item = li[e], a = lu[e], d = sd[e], s_ = ss[e];
        int b0 = item >> 9;
        int r0 = atomicAdd(&lc[b0], 1);
        partLI[go[b0] + r0] = (a << 9) | (item & 511);
        if (mask & (1u << i)) {
            int b1 = 256 + (a >> 9);
            int r1 = atomicAdd(&lc[b1], 1);
            partLU[go[b1] + r1] = (item << 9) | (a & 511);
        }
        int b2 = 512 + (d >> 9);
        int r2 = atomicAdd(&lc[b2], 1);
        partSD[go[b2] + r2] = (s_ << 9) | (d & 511);
    }
}

// ---- pass D: one block per bucket; count/scan -> deg/start + rank-scatter ----
__global__ void k_passD(const int* __restrict__ gcnt, const int* __restrict__ gbase,
                        const int* __restrict__ partLI, const int* __restrict__ partLU,
                        const int* __restrict__ partSD, int* __restrict__ csrli,
                        int* __restrict__ csrlu, int* __restrict__ csrsd,
                        int* __restrict__ ideg, int* __restrict__ udeg,
                        int* __restrict__ sdeg, int* __restrict__ istart,
                        int* __restrict__ ustart, int* __restrict__ sstart) {
    __shared__ int lcnt[512], lstart[512], sb[2][512];
    int t = threadIdx.x;
    int blk = blockIdx.x, list, b;
    const int* part; int* csr; int* deg; int* start; int n;
    if (blk < 196)      { list = 0; b = blk;       part = partLI; csr = csrli; deg = ideg; start = istart; n = NITEMS; }
    else if (blk < 392) { list = 1; b = blk - 196; part = partLU; csr = csrlu; deg = udeg; start = ustart; n = NUSERS; }
    else                { list = 2; b = blk - 392; part = partSD; csr = csrsd; deg = sdeg; start = sstart; n = NUSERS; }
    int base = gbase[list * 256 + b], cnt = gcnt[list * 256 + b];
    int node0 = b << 9;
    int M = n - node0; if (M > 512) M = 512; if (M < 0) M = 0;

    lcnt[t] = 0; lcnt[t + 256] = 0;
    __syncthreads();
    for (int i = t; i < cnt; i += 256) atomicAdd(&lcnt[part[base + i] & 511], 1);
    __syncthreads();
    sb[0][t] = lcnt[t]; sb[0][t + 256] = lcnt[t + 256];
    __syncthreads();
    int pp = 0;
    for (int o = 1; o < 512; o <<= 1) {
        int np = pp ^ 1;
        for (int k = t; k < 512; k += 256) {
            int v = sb[pp][k];
            if (k >= o) v += sb[pp][k - o];
            sb[np][k] = v;
        }
        __syncthreads();
        pp = np;
    }
    for (int k = t; k < 512; k += 256) {
        int ex = sb[pp][k] - lcnt[k];       // exclusive scan
        lstart[k] = ex;
        if (k < M) { deg[node0 + k] = lcnt[k]; start[node0 + k] = base + ex; }
    }
    __syncthreads();
    lcnt[t] = 0; lcnt[t + 256] = 0;
    __syncthreads();
    for (int i = t; i < cnt; i += 256) {
        int p = part[base + i];
        int nl = p & 511;
        int r = atomicAdd(&lcnt[nl], 1);
        csr[base + lstart[nl] + r] = p >> 9;  // window stays in one XCD's L2
    }
}

// ---- epilogue helpers (value args -> stays in registers, rule #20) ----
__device__ __forceinline__ void item_store(int n, int dg, const float* __restrict__ iemb,
                                           u16* __restrict__ rec, int l8,
                                           const float* __restrict__ s) {
    float dgf = (float)dg;
    float inv = 1.0f / fmaxf(dgf, 1.0f);
    float sw  = 1.0f - dgf / (dgf + 1e-8f);
    float4 e0 = ((const float4*)(iemb + n * 64))[l8 * 2];
    float4 e1 = ((const float4*)(iemb + n * 64))[l8 * 2 + 1];
    uint4 o;
    o.x = (unsigned)f2bf(sw * e0.x + s[0] * inv) | ((unsigned)f2bf(sw * e0.y + s[1] * inv) << 16);
    o.y = (unsigned)f2bf(sw * e0.z + s[2] * inv) | ((unsigned)f2bf(sw * e0.w + s[3] * inv) << 16);
    o.z = (unsigned)f2bf(sw * e1.x + s[4] * inv) | ((unsigned)f2bf(sw * e1.y + s[5] * inv) << 16);
    o.w = (unsigned)f2bf(sw * e1.z + s[6] * inv) | ((unsigned)f2bf(sw * e1.w + s[7] * inv) << 16);
    ((uint4*)(rec + n * 128 + 64))[l8] = o;          // hi half of record
}
__device__ __forceinline__ void soc_store(int n, int dg, unsigned* __restrict__ soc1, int l8,
                                          const float* __restrict__ s) {
    float inv = 1.0f / fmaxf((float)dg, 1.0f);
    uint4 o;
    o.x = (unsigned)f2bf(s[0] * inv) | ((unsigned)f2bf(s[1] * inv) << 16);
    o.y = (unsigned)f2bf(s[2] * inv) | ((unsigned)f2bf(s[3] * inv) << 16);
    o.z = (unsigned)f2bf(s[4] * inv) | ((unsigned)f2bf(s[5] * inv) << 16);
    o.w = (unsigned)f2bf(s[6] * inv) | ((unsigned)f2bf(s[7] * inv) << 16);
    ((uint4*)(soc1 + n * 32))[l8] = o;
}

// ---- core: gather-mean of FOUR bf16 rowsets concurrently. dwordx4 row
//      gathers (8 lanes per 128-B row); UNCONDITIONAL clamped loads; 8 x 1KB
//      loads in flight per iteration (2x the pair version). Per-node
//      accumulation order identical to the pair version (bitwise-same). ----
__device__ __forceinline__ void gather_quad(const unsigned* __restrict__ uh32,
                                            const int* __restrict__ csr,
                                            int jA, int dA, int jB, int dB,
                                            int jC, int dC, int jD, int dD,
                                            int lane, int g, int l8,
                                            float* __restrict__ aA, float* __restrict__ aB,
                                            float* __restrict__ aC, float* __restrict__ aD) {
    int cA = (lane < dA) ? csr[jA + lane] : 0;
    int cB = (lane < dB) ? csr[jB + lane] : 0;
    int cC = (lane < dC) ? csr[jC + lane] : 0;
    int cD = (lane < dD) ? csr[jD + lane] : 0;
    int kmA = dA < 64 ? dA : 64, kmB = dB < 64 ? dB : 64;
    int kmC = dC < 64 ? dC : 64, kmD = dD < 64 ? dD : 64;
    int clA = kmA > 0 ? kmA - 1 : 0, clB = kmB > 0 ? kmB - 1 : 0;
    int clC = kmC > 0 ? kmC - 1 : 0, clD = kmD > 0 ? kmD - 1 : 0;
    int km = kmA > kmB ? kmA : kmB;
    if (kmC > km) km = kmC;
    if (kmD > km) km = kmD;
    for (int k = 0; k < km; k += 16) {
        int q0 = k + g, q1 = k + 8 + g;
        int iA0 = q0 < kmA ? q0 : clA, iA1 = q1 < kmA ? q1 : clA;
        int iB0 = q0 < kmB ? q0 : clB, iB1 = q1 < kmB ? q1 : clB;
        int iC0 = q0 < kmC ? q0 : clC, iC1 = q1 < kmC ? q1 : clC;
        int iD0 = q0 < kmD ? q0 : clD, iD1 = q1 < kmD ? q1 : clD;
        int rA0 = __shfl(cA, iA0), rA1 = __shfl(cA, iA1);
        int rB0 = __shfl(cB, iB0), rB1 = __shfl(cB, iB1);
        int rC0 = __shfl(cC, iC0), rC1 = __shfl(cC, iC1);
        int rD0 = __shfl(cD, iD0), rD1 = __shfl(cD, iD1);
        uint4 wA0 = *(const uint4*)(uh32 + rA0 * 32 + l8 * 4);
        uint4 wA1 = *(const uint4*)(uh32 + rA1 * 32 + l8 * 4);
        uint4 wB0 = *(const uint4*)(uh32 + rB0 * 32 + l8 * 4);
        uint4 wB1 = *(const uint4*)(uh32 + rB1 * 32 + l8 * 4);
        uint4 wC0 = *(const uint4*)(uh32 + rC0 * 32 + l8 * 4);
        uint4 wC1 = *(const uint4*)(uh32 + rC1 * 32 + l8 * 4);
        uint4 wD0 = *(const uint4*)(uh32 + rD0 * 32 + l8 * 4);
        uint4 wD1 = *(const uint4*)(uh32 + rD1 * 32 + l8 * 4);
        if (q0 < kmA) acc8(wA0, aA);
        if (q1 < kmA) acc8(wA1, aA);
        if (q0 < kmB) acc8(wB0, aB);
        if (q1 < kmB) acc8(wB1, aB);
        if (q0 < kmC) acc8(wC0, aC);
        if (q1 < kmC) acc8(wC1, aC);
        if (q0 < kmD) acc8(wD0, aD);
        if (q1 < kmD) acc8(wD1, aD);
    }
    for (int k = 64; k < dA; k += 8) {        // deg>64 tails (rare)
        int q = k + g; int idx = q < dA ? q : dA - 1;
        uint4 w = *(const uint4*)(uh32 + csr[jA + idx] * 32 + l8 * 4);
        if (q < dA) acc8(w, aA);
    }
    for (int k = 64; k < dB; k += 8) {
        int q = k + g; int idx = q < dB ? q : dB - 1;
        uint4 w = *(const uint4*)(uh32 + csr[jB + idx] * 32 + l8 * 4);
        if (q < dB) acc8(w, aB);
    }
    for (int k = 64; k < dC; k += 8) {
        int q = k + g; int idx = q < dC ? q : dC - 1;
        uint4 w = *(const uint4*)(uh32 + csr[jC + idx] * 32 + l8 * 4);
        if (q < dC) acc8(w, aC);
    }
    for (int k = 64; k < dD; k += 8) {
        int q = k + g; int idx = q < dD ? q : dD - 1;
        uint4 w = *(const uint4*)(uh32 + csr[jD + idx] * 32 + l8 * 4);
        if (q < dD) acc8(w, aD);
    }
    #pragma unroll
    for (int off = 8; off <= 32; off <<= 1) {
        #pragma unroll
        for (int m = 0; m < 8; ++m) {
            aA[m] += __shfl_xor(aA[m], off);
            aB[m] += __shfl_xor(aB[m], off);
            aC[m] += __shfl_xor(aC[m], off);
            aD[m] += __shfl_xor(aD[m], off);
        }
    }
}

// ---- fused gather: items (rec hi-half) and social users (soc1), FOUR nodes
//      per wave for 2x memory-level parallelism ----
__global__ void k_gather_fused(const float* __restrict__ iemb,
                               const unsigned* __restrict__ uh32,
                               const int* __restrict__ csrli, const int* __restrict__ istart,
                               const int* __restrict__ ideg, u16* __restrict__ rec,
                               const int* __restrict__ csrsd, const int* __restrict__ sstart,
                               const int* __restrict__ sdeg,
                               const unsigned char* __restrict__ needed,
                               unsigned* __restrict__ soc1) {
    int lane = threadIdx.x & 63;
    int wid  = blockIdx.x * 4 + (threadIdx.x >> 6);
    int nw   = gridDim.x * 4;
    int g = lane >> 3, l8 = lane & 7;
    const int NQI = NITEMS / 4;               // 12500 item quads
    const int NQ  = NQI + NUSERS / 4;         // + 25000 soc quads
    for (int w = wid; w < NQ; w += nw) {
        float aA[8] = {0.f,0.f,0.f,0.f,0.f,0.f,0.f,0.f};
        float aB[8] = {0.f,0.f,0.f,0.f,0.f,0.f,0.f,0.f};
        float aC[8] = {0.f,0.f,0.f,0.f,0.f,0.f,0.f,0.f};
        float aD[8] = {0.f,0.f,0.f,0.f,0.f,0.f,0.f,0.f};
        if (w < NQI) {
            int n0 = w * 4;
            int jA = istart[n0],     dA = ideg[n0];
            int jB = istart[n0 + 1], dB = ideg[n0 + 1];
            int jC = istart[n0 + 2], dC = ideg[n0 + 2];
            int jD = istart[n0 + 3], dD = ideg[n0 + 3];
            gather_quad(uh32, csrli, jA, dA, jB, dB, jC, dC, jD, dD,
                        lane, g, l8, aA, aB, aC, aD);
            if (g == 0)      item_store(n0,     dA, iemb, rec, l8, aA);
            else if (g == 1) item_store(n0 + 1, dB, iemb, rec, l8, aB);
            else if (g == 2) item_store(n0 + 2, dC, iemb, rec, l8, aC);
            else if (g == 3) item_store(n0 + 3, dD, iemb, rec, l8, aD);
        } else {
            int n0 = (w - NQI) * 4;
            unsigned nd = *(const unsigned*)(needed + n0);   // n0 % 4 == 0
            if (!nd) continue;                // none of the 4 rows ever read
            int needA = nd & 0xff, needB = (nd >> 8) & 0xff;
            int needC = (nd >> 16) & 0xff, needD = nd >> 24;
            int jA = sstart[n0],     dA = needA ? sdeg[n0]     : 0;
            int jB = sstart[n0 + 1], dB = needB ? sdeg[n0 + 1] : 0;
            int jC = sstart[n0 + 2], dC = needC ? sdeg[n0 + 2] : 0;
            int jD = sstart[n0 + 3], dD = needD ? sdeg[n0 + 3] : 0;
            gather_quad(uh32, csrsd, jA, dA, jB, dB, jC, dC, jD, dD,
                        lane, g, l8, aA, aB, aC, aD);
            if (g == 0)      { if (needA) soc_store(n0,     dA, soc1, l8, aA); }
            else if (g == 1) { if (needB) soc_store(n0 + 1, dB, soc1, l8, aB); }
            else if (g == 2) { if (needC) soc_store(n0 + 2, dC, soc1, l8, aC); }
            else if (g == 3) { if (needD) soc_store(n0 + 3, dD, soc1, l8, aD); }
        }
    }
}

// ---- fused epilogue: TWO batch elements per wave, interleaved.
//      Rating means read the item record (iembh|ri1 adjacent lines);
//      ru1/ru2 stay f32 in registers. ----
__global__ void k_final2(const int* __restrict__ users, const int* __restrict__ items,
                         const float* __restrict__ uemb, const float* __restrict__ iemb,
                         const u16* __restrict__ rec, const int* __restrict__ csrlu,
                         const int* __restrict__ ustart, const int* __restrict__ udeg,
                         const u16* __restrict__ soc1, const int* __restrict__ csrsd,
                         const int* __restrict__ sstart, const int* __restrict__ sdeg,
                         float* __restrict__ out) {
    int d   = threadIdx.x & 63;
    int wid = blockIdx.x * 4 + (threadIdx.x >> 6);
    if (wid >= NBATCH / 2) return;
    int bA = wid, bB = wid + NBATCH / 2;
    int uA = users[bA], uB = users[bB];
    int itA = items[bA], itB = items[bB];
    int juA = ustart[uA], duA = udeg[uA];
    int juB = ustart[uB], duB = udeg[uB];
    int jsA = sstart[uA], dsA = sdeg[uA];
    int jsB = sstart[uB], dsB = sdeg[uB];
    int cvUA = (d < duA) ? csrlu[juA + d] : 0;
    int cvUB = (d < duB) ? csrlu[juB + d] : 0;
    int cvSA = (d < dsA) ? csrsd[jsA + d] : 0;
    int cvSB = (d < dsB) ? csrsd[jsB + d] : 0;
    // ---- rating means over like-lists (both elements interleaved) ----
    int kmuA = duA < 64 ? duA : 64, cluA = kmuA > 0 ? kmuA - 1 : 0;
    int kmuB = duB < 64 ? duB : 64, cluB = kmuB > 0 ? kmuB - 1 : 0;
    int kmu = kmuA > kmuB ? kmuA : kmuB;
    float pA0=0.f,pA1=0.f,pA2=0.f,pA3=0.f, qA0=0.f,qA1=0.f,qA2=0.f,qA3=0.f;
    float pB0=0.f,pB1=0.f,pB2=0.f,pB3=0.f, qB0=0.f,qB1=0.f,qB2=0.f,qB3=0.f;
    for (int k = 0; k < kmu; k += 4) {
        int xA0 = k   < kmuA ? k   : cluA, xA1 = k+1 < kmuA ? k+1 : cluA;
        int xA2 = k+2 < kmuA ? k+2 : cluA, xA3 = k+3 < kmuA ? k+3 : cluA;
        int xB0 = k   < kmuB ? k   : cluB, xB1 = k+1 < kmuB ? k+1 : cluB;
        int xB2 = k+2 < kmuB ? k+2 : cluB, xB3 = k+3 < kmuB ? k+3 : cluB;
        int iA0 = __shfl(cvUA, xA0), iA1 = __shfl(cvUA, xA1);
        int iA2 = __shfl(cvUA, xA2), iA3 = __shfl(cvUA, xA3);
        int iB0 = __shfl(cvUB, xB0), iB1 = __shfl(cvUB, xB1);
        int iB2 = __shfl(cvUB, xB2), iB3 = __shfl(cvUB, xB3);
        float tA0 = bf2f(rec[iA0*128 + d]),      tA1 = bf2f(rec[iA1*128 + d]);
        float tA2 = bf2f(rec[iA2*128 + d]),      tA3 = bf2f(rec[iA3*128 + d]);
        float rA0 = bf2f(rec[iA0*128 + 64 + d]), rA1 = bf2f(rec[iA1*128 + 64 + d]);
        float rA2 = bf2f(rec[iA2*128 + 64 + d]), rA3 = bf2f(rec[iA3*128 + 64 + d]);
        float tB0 = bf2f(rec[iB0*128 + d]),      tB1 = bf2f(rec[iB1*128 + d]);
        float tB2 = bf2f(rec[iB2*128 + d]),      tB3 = bf2f(rec[iB3*128 + d]);
        float rB0 = bf2f(rec[iB0*128 + 64 + d]), rB1 = bf2f(rec[iB1*128 + 64 + d]);
        float rB2 = bf2f(rec[iB2*128 + 64 + d]), rB3 = bf2f(rec[iB3*128 + 64 + d]);
        if (k   < kmuA) { pA0 += tA0; qA0 += rA0; }
        if (k+1 < kmuA) { pA1 += tA1; qA1 += rA1; }
        if (k+2 < kmuA) { pA2 += tA2; qA2 += rA2; }
        if (k+3 < kmuA) { pA3 += tA3; qA3 += rA3; }
        if (k   < kmuB) { pB0 += tB0; qB0 += rB0; }
        if (k+1 < kmuB) { pB1 += tB1; qB1 += rB1; }
        if (k+2 < kmuB) { pB2 += tB2; qB2 += rB2; }
        if (k+3 < kmuB) { pB3 += tB3; qB3 += rB3; }
    }
    for (int j = juA + 64; j < juA + duA; ++j) {      // deg>64 tail (rare)
        int i0 = csrlu[j];
        pA0 += bf2f(rec[i0*128 + d]); qA0 += bf2f(rec[i0*128 + 64 + d]);
    }
    for (int j = juB + 64; j < juB + duB; ++j) {
        int i0 = csrlu[j];
        pB0 += bf2f(rec[i0*128 + d]); qB0 += bf2f(rec[i0*128 + 64 + d]);
    }
    // ---- social means over in-lists (both elements interleaved) ----
    int kmsA = dsA < 64 ? dsA : 64, clsA = kmsA > 0 ? kmsA - 1 : 0;
    int kmsB = dsB < 64 ? dsB : 64, clsB = kmsB > 0 ? kmsB - 1 : 0;
    int kms = kmsA > kmsB ? kmsA : kmsB;
    float sA0=0.f,sA1=0.f,sA2=0.f,sA3=0.f, sB0=0.f,sB1=0.f,sB2=0.f,sB3=0.f;
    for (int k = 0; k < kms; k += 4) {
        int xA0 = k   < kmsA ? k   : clsA, xA1 = k+1 < kmsA ? k+1 : clsA;
        int xA2 = k+2 < kmsA ? k+2 : clsA, xA3 = k+3 < kmsA ? k+3 : clsA;
        int xB0 = k   < kmsB ? k   : clsB, xB1 = k+1 < kmsB ? k+1 : clsB;
        int xB2 = k+2 < kmsB ? k+2 : clsB, xB3 = k+3 < kmsB ? k+3 : clsB;
        int cA0 = __shfl(cvSA, xA0), cA1 = __shfl(cvSA, xA1);
        int cA2 = __shfl(cvSA, xA2), cA3 = __shfl(cvSA, xA3);
        int cB0 = __shfl(cvSB, xB0), cB1 = __shfl(cvSB, xB1);
        int cB2 = __shfl(cvSB, xB2), cB3 = __shfl(cvSB, xB3);
        float fA0 = bf2f(soc1[cA0*64 + d]), fA1 = bf2f(soc1[cA1*64 + d]);
        float fA2 = bf2f(soc1[cA2*64 + d]), fA3 = bf2f(soc1[cA3*64 + d]);
        float fB0 = bf2f(soc1[cB0*64 + d]), fB1 = bf2f(soc1[cB1*64 + d]);
        float fB2 = bf2f(soc1[cB2*64 + d]), fB3 = bf2f(soc1[cB3*64 + d]);
        if (k   < kmsA) sA0 += fA0;
        if (k+1 < kmsA) sA1 += fA1;
        if (k+2 < kmsA) sA2 += fA2;
        if (k+3 < kmsA) sA3 += fA3;
        if (k   < kmsB) sB0 += fB0;
        if (k+1 < kmsB) sB1 += fB1;
        if (k+2 < kmsB) sB2 += fB2;
        if (k+3 < kmsB) sB3 += fB3;
    }
    for (int j = jsA + 64; j < jsA + dsA; ++j)        // deg>64 tail (rare)
        sA0 += bf2f(soc1[csrsd[j]*64 + d]);
    for (int j = jsB + 64; j < jsB + dsB; ++j)
        sB0 += bf2f(soc1[csrsd[j]*64 + d]);
    // ---- combine + write, element A ----
    {
        float invU = 1.0f / fmaxf((float)duA, 1.0f);
        float ru1 = ((pA0 + pA1) + (pA2 + pA3)) * invU;
        float ru2 = ((qA0 + qA1) + (qA2 + qA3)) * invU;
        float s2 = ((sA0 + sA1) + (sA2 + sA3)) / fmaxf((float)dsA, 1.0f);
        float ud = (float)duA;
        float usw = 1.0f - ud / (ud + 1e-8f);
        float ue = uemb[uA * 64 + d];
        float s1 = bf2f(soc1[uA * 64 + d]);
        float r1 = usw * ue + ru1;
        float r2 = usw * r1 + ru2;
        float fu = ue + 0.5f * (s1 + r1) + 0.5f * (s2 + r2);
        float iv = iemb[itA * 64 + d];
        out[NBATCH + bA * 64 + d]               = fu;
        out[NBATCH + NBATCH * 64 + bA * 64 + d] = iv;
        float p = fu * iv;
        #pragma unroll
        for (int o = 32; o > 0; o >>= 1) p += __shfl_down(p, o);
        if (d == 0) out[bA] = 1.0f / (1.0f + __expf(-p));
    }
    // ---- combine + write, element B ----
    {
        float invU = 1.0f / fmaxf((float)duB, 1.0f);
        float ru1 = ((pB0 + pB1) + (pB2 + pB3)) * invU;
        float ru2 = ((qB0 + qB1) + (qB2 + qB3)) * invU;
        float s2 = ((sB0 + sB1) + (sB2 + sB3)) / fmaxf((float)dsB, 1.0f);
        float ud = (float)duB;
        float usw = 1.0f - ud / (ud + 1e-8f);
        float ue = uemb[uB * 64 + d];
        float s1 = bf2f(soc1[uB * 64 + d]);
        float r1 = usw * ue + ru1;
        float r2 = usw * r1 + ru2;
        float fu = ue + 0.5f * (s1 + r1) + 0.5f * (s2 + r2);
        float iv = iemb[itB * 64 + d];
        out[NBATCH + bB * 64 + d]               = fu;
        out[NBATCH + NBATCH * 64 + bB * 64 + d] = iv;
        float p = fu * iv;
        #pragma unroll
        for (int o = 32; o > 0; o >>= 1) p += __shfl_down(p, o);
        if (d == 0) out[bB] = 1.0f / (1.0f + __expf(-p));
    }
}

extern "C" void kernel_launch(void* const* d_in, const int* in_sizes, int n_in,
                              void* d_out, int out_size, void* d_ws, size_t ws_size,
                              hipStream_t stream) {
    const float* uemb  = (const float*)d_in[0];
    const float* iemb  = (const float*)d_in[1];
    const int*   users = (const int*)d_in[2];
    const int*   items = (const int*)d_in[3];
    const int*   ssrc  = (const int*)d_in[4];
    const int*   sdst  = (const int*)d_in[5];
    const int*   lu    = (const int*)d_in[6];
    const int*   li    = (const int*)d_in[7];
    float* out = (float*)d_out;

    if (ws_size < (size_t)WS_FLOATS * 4) return;  // would show absmax==0.5 diagnostic

    int*           W      = (int*)d_ws;
    int*           gcnt   = W + OFF_GC;
    int*           gbase  = W + OFF_GB;
    int*           gcur   = W + OFF_GCUR;
    unsigned*      bits   = (unsigned*)(W + OFF_BITS);
    unsigned char* needed = (unsigned char*)(W + OFF_NEED);
    int*           ideg   = W + OFF_IDEG;
    int*           udeg   = W + OFF_UDEG;
    int*           sdeg   = W + OFF_SDEG;
    int*           istart = W + OFF_ISTART;
    int*           ustart = W + OFF_USTART;
    int*           sstart = W + OFF_SSTART;
    u16*           uembh  = (u16*)(W + OFF_UEMBH);
    u16*           rec    = (u16*)(W + OFF_REC);
    u16*           soc1   = (u16*)(W + OFF_SOC1);
    int*           partLI = W + OFF_PARTLI;
    int*           partLU = W + OFF_PARTLU;
    int*           partSD = W + OFF_PARTSD;
    int*           csrli  = W + OFF_CSRLI;
    int*           csrlu  = W + OFF_CSRLU;
    int*           csrsd  = W + OFF_CSRSD;

    hipMemsetAsync(d_ws, 0, (size_t)OFF_ZEND * 4, stream);   // gcnt + bits + needed

    const int B = 256;

    // bf16 shadows + batch membership (one kernel; no build dependency)
    k_init<<<NB_INIT, B, 0, stream>>>(uemb, iemb, users, uembh, rec, bits, needed);

    // CSR build (bucket-partitioned, chunked writes, LDS-bitmask membership)
    k_passA<<<NBLK_E, B, 0, stream>>>(lu, li, sdst, ssrc, bits, gcnt, needed);
    k_passB<<<1, B, 0, stream>>>(gcnt, gbase, gcur);
    k_passC<<<NBLK_E, B, 0, stream>>>(lu, li, sdst, ssrc, bits, gcur,
                                      partLI, partLU, partSD);
    k_passD<<<588, B, 0, stream>>>(gcnt, gbase, partLI, partLU, partSD,
                                   csrli, csrlu, csrsd, ideg, udeg, sdeg,
                                   istart, ustart, sstart);

    // fused item + social gathers (4 nodes per wave, 8x1KB loads in flight)
    k_gather_fused<<<GGRID, B, 0, stream>>>(iemb, (const unsigned*)uembh,
                                            csrli, istart, ideg, rec,
                                            csrsd, sstart, sdeg, needed,
                                            (unsigned*)soc1);

    // fused rating means + social mean + epilogue (2 elements per wave)
    k_final2<<<2048, B, 0, stream>>>(users, items, uemb, iemb, rec, csrlu,
                                     ustart, udeg, soc1, csrsd, sstart, sdeg, out);
}

// Round 7
// 251.720 us; speedup vs baseline: 2.8769x; 1.0287x over previous
//
#include <hip/hip_runtime.h>
#include <hip/hip_bf16.h>

#define NUSERS 100000
#define NITEMS 50000
#define NEDGE  1000000
#define NBATCH 16384
#define CAP_LU 320000     // filtered like-edges of batch users; expected ~164K (2x margin)
#define EPB    2048       // edges per block in passA/passC (8 per thread)
#define NBLK_E ((NEDGE + EPB - 1) / EPB)   // 489
#define NBW    3125       // NUSERS/32 bitmask words
#define GGRID  2048       // persistent grid: 256 CU x 8 blocks (256thr)
#define NB_CVT 9375       // (NUSERS+NITEMS)*16 / 256 float4-cvt blocks

// ---- workspace layout, units of 4 bytes; total 14,770,464 units = 59.1 MB ----
// All bf16 row arrays (uembh / rec / soc1) are 128-B aligned.
// rec = per-item 256-B record: [128B iembh row | 128B ri1 row].
#define OFF_GC     0                          // 256*3 bucket counts (memset 0)
#define OFF_GB     768
#define OFF_GCUR   1536
#define OFF_BITS   2304                       // 3136 u32 batch-membership bitmask
#define OFF_NEED   (OFF_BITS + 3136)          // NUSERS bytes = 25000 units
#define OFF_ZEND   (OFF_NEED + NUSERS / 4)    // 30,440 end of memset-0 region
#define OFF_IDEG   OFF_ZEND
#define OFF_UDEG   (OFF_IDEG + NITEMS)
#define OFF_SDEG   (OFF_UDEG + NUSERS)
#define OFF_ISTART (OFF_SDEG + NUSERS)
#define OFF_USTART (OFF_ISTART + NITEMS)
#define OFF_SSTART (OFF_USTART + NUSERS)
#define OFF_UEMBH  530464                     // NUSERS*32 (bf16 uemb shadow), 128-B aligned
#define OFF_REC    (OFF_UEMBH + NUSERS * 32)  // NITEMS*64 (iembh|ri1 records)
#define OFF_SOC1   (OFF_REC + NITEMS * 64)    // NUSERS*32
#define OFF_PARTLI (OFF_SOC1 + NUSERS * 32)
#define OFF_PARTLU (OFF_PARTLI + NEDGE)
#define OFF_PARTSD (OFF_PARTLU + CAP_LU)
#define OFF_CSRLI  (OFF_PARTSD + NEDGE)
#define OFF_CSRLU  (OFF_CSRLI + NEDGE)
#define OFF_CSRSD  (OFF_CSRLU + CAP_LU)
#define WS_FLOATS  (OFF_CSRSD + NEDGE)        // 14,770,464

typedef unsigned short u16;

__device__ __forceinline__ float bf2f(u16 h) {
    union { unsigned u; float f; } c; c.u = ((unsigned)h) << 16; return c.f;
}
__device__ __forceinline__ u16 f2bf(float f) {
    union { float f; unsigned u; } c; c.f = f;
    unsigned r = c.u + 0x7fffu + ((c.u >> 16) & 1u);   // RNE
    return (u16)(r >> 16);
}
__device__ __forceinline__ void acc2(unsigned w, float& a0, float& a1) {
    a0 += bf2f((u16)(w & 0xffff));
    a1 += bf2f((u16)(w >> 16));
}
__device__ __forceinline__ void acc8(uint4 w, float* a) {
    acc2(w.x, a[0], a[1]); acc2(w.y, a[2], a[3]);
    acc2(w.z, a[4], a[5]); acc2(w.w, a[6], a[7]);
}

// ---- slot: batch membership bitmask + needed flags (must precede passA) ----
__global__ void k_slot(const int* __restrict__ users, unsigned* __restrict__ bits,
                       unsigned char* __restrict__ needed) {
    int b = blockIdx.x * blockDim.x + threadIdx.x;
    if (b < NBATCH) {
        int u = users[b];
        atomicOr(&bits[u >> 5], 1u << (u & 31));
        needed[u] = 1;
    }
}

// ---- cvt + passA merged: blocks [0,NB_CVT) do bf16 shadows (independent of
//      slot); blocks [NB_CVT, NB_CVT+NBLK_E) do passA histograms (need bits).
//      Overlaps the cvt streaming with passA's edge scan; one fewer dispatch. ----
__global__ void k_cvtA(const float* __restrict__ uemb, const float* __restrict__ iemb,
                       const int* __restrict__ lu, const int* __restrict__ li,
                       const int* __restrict__ sd, const int* __restrict__ ss,
                       const unsigned* __restrict__ bits, int* __restrict__ gcnt,
                       unsigned char* __restrict__ needed,
                       u16* __restrict__ uembh, u16* __restrict__ rec) {
    int blk = blockIdx.x;
    if (blk < NB_CVT) {
        int t = blk * 256 + threadIdx.x;
        if (t < NUSERS * 16) {
            float4 v = ((const float4*)uemb)[t];
            ushort4 o;
            o.x = f2bf(v.x); o.y = f2bf(v.y); o.z = f2bf(v.z); o.w = f2bf(v.w);
            ((ushort4*)uembh)[t] = o;
        } else {
            int t2 = t - NUSERS * 16;                 // < NITEMS*16
            int i = t2 >> 4, c = t2 & 15;             // item, chunk of 4 dims
            float4 v = ((const float4*)iemb)[t2];
            ushort4 o;
            o.x = f2bf(v.x); o.y = f2bf(v.y); o.z = f2bf(v.z); o.w = f2bf(v.w);
            ((ushort4*)rec)[i * 32 + c] = o;          // lo half of record
        }
        return;
    }
    // ---- passA part ----
    __shared__ int lc[768];
    __shared__ unsigned sbits[NBW];
    int t = threadIdx.x;
    for (int k = t; k < 768; k += 256) lc[k] = 0;
    for (int k = t; k < NBW; k += 256) sbits[k] = bits[k];
    __syncthreads();
    int base = (blk - NB_CVT) * EPB;
    int end = base + EPB; if (end > NEDGE) end = NEDGE;
    for (int e = base + t; e < end; e += 256) {
        int item = li[e], a = lu[e], d = sd[e];
        atomicAdd(&lc[item >> 9], 1);                        // list0: by item
        if ((sbits[a >> 5] >> (a & 31)) & 1)                 // list1: batch users
            atomicAdd(&lc[256 + (a >> 9)], 1);
        atomicAdd(&lc[512 + (d >> 9)], 1);                   // list2: by dst user
        if ((sbits[d >> 5] >> (d & 31)) & 1)                 // soc1 needed at source
            needed[ss[e]] = 1;
    }
    __syncthreads();
    for (int k = t; k < 768; k += 256)
        if (lc[k]) atomicAdd(&gcnt[k], lc[k]);
}

// ---- pass B: one block; 3 exclusive scans of 256 bucket counts ----
__global__ void k_passB(const int* __restrict__ gcnt, int* __restrict__ gbase,
                        int* __restrict__ gcur) {
    __shared__ int s[256];
    int t = threadIdx.x;
    for (int j = 0; j < 3; ++j) {
        int v = gcnt[j * 256 + t];
        s[t] = v;
        __syncthreads();
        for (int o = 1; o < 256; o <<= 1) {
            int x = (t >= o) ? s[t - o] : 0;
            __syncthreads();
            s[t] += x;
            __syncthreads();
        }
        int ex = s[t] - v;
        gbase[j * 256 + t] = ex;
        gcur[j * 256 + t] = ex;
        __syncthreads();
    }
}

// ---- pass C: partition edges into per-bucket chunks ----
__global__ void k_passC(const int* __restrict__ lu, const int* __restrict__ li,
                        const int* __restrict__ sd, const int* __restrict__ ss,
                        const unsigned* __restrict__ bits, int* __restrict__ gcur,
                        int* __restrict__ partLI, int* __restrict__ partLU,
                        int* __restrict__ partSD) {
    __shared__ int lc[768];   // local counts, then rank counters
    __shared__ int go[768];   // this block's global chunk offsets
    __shared__ unsigned sbits[NBW];
    int t = threadIdx.x;
    for (int k = t; k < 768; k += 256) lc[k] = 0;
    for (int k = t; k < NBW; k += 256) sbits[k] = bits[k];
    __syncthreads();
    int base = blockIdx.x * EPB;
    int end = base + EPB; if (end > NEDGE) end = NEDGE;
    unsigned mask = 0;        // bit i: edge (base + i*256 + t) belongs to a batch user
    int i = 0;
    for (int e = base + t; e < end; e += 256, ++i) {
        int item = li[e], a = lu[e], d = sd[e];
        atomicAdd(&lc[item >> 9], 1);
        if ((sbits[a >> 5] >> (a & 31)) & 1) {
            atomicAdd(&lc[256 + (a >> 9)], 1);
            mask |= (1u << i);
        }
        atomicAdd(&lc[512 + (d >> 9)], 1);
    }
    __syncthreads();
    for (int k = t; k < 768; k += 256) {
        go[k] = lc[k] ? atomicAdd(&gcur[k], lc[k]) : 0;
        lc[k] = 0;
    }
    __syncthreads();
    i = 0;
    for (int e = base + t; e < end; e += 256, ++i) {
        int item = li[e], a = lu[e], d = sd[e], s_ = ss[e];
        int b0 = item >> 9;
        int r0 = atomicAdd(&lc[b0], 1);
        partLI[go[b0] + r0] = (a << 9) | (item & 511);
        if (mask & (1u << i)) {
            int b1 = 256 + (a >> 9);
            int r1 = atomicAdd(&lc[b1], 1);
            partLU[go[b1] + r1] = (item << 9) | (a & 511);
        }
        int b2 = 512 + (d >> 9);
        int r2 = atomicAdd(&lc[b2], 1);
        partSD[go[b2] + r2] = (s_ << 9) | (d & 511);
    }
}

// ---- pass D: one block per bucket; count/scan -> deg/start + rank-scatter ----
__global__ void k_passD(const int* __restrict__ gcnt, const int* __restrict__ gbase,
                        const int* __restrict__ partLI, const int* __restrict__ partLU,
                        const int* __restrict__ partSD, int* __restrict__ csrli,
                        int* __restrict__ csrlu, int* __restrict__ csrsd,
                        int* __restrict__ ideg, int* __restrict__ udeg,
                        int* __restrict__ sdeg, int* __restrict__ istart,
                        int* __restrict__ ustart, int* __restrict__ sstart) {
    __shared__ int lcnt[512], lstart[512], sb[2][512];
    int t = threadIdx.x;
    int blk = blockIdx.x, list, b;
    const int* part; int* csr; int* deg; int* start; int n;
    if (blk < 196)      { list = 0; b = blk;       part = partLI; csr = csrli; deg = ideg; start = istart; n = NITEMS; }
    else if (blk < 392) { list = 1; b = blk - 196; part = partLU; csr = csrlu; deg = udeg; start = ustart; n = NUSERS; }
    else                { list = 2; b = blk - 392; part = partSD; csr = csrsd; deg = sdeg; start = sstart; n = NUSERS; }
    int base = gbase[list * 256 + b], cnt = gcnt[list * 256 + b];
    int node0 = b << 9;
    int M = n - node0; if (M > 512) M = 512; if (M < 0) M = 0;

    lcnt[t] = 0; lcnt[t + 256] = 0;
    __syncthreads();
    for (int i = t; i < cnt; i += 256) atomicAdd(&lcnt[part[base + i] & 511], 1);
    __syncthreads();
    sb[0][t] = lcnt[t]; sb[0][t + 256] = lcnt[t + 256];
    __syncthreads();
    int pp = 0;
    for (int o = 1; o < 512; o <<= 1) {
        int np = pp ^ 1;
        for (int k = t; k < 512; k += 256) {
            int v = sb[pp][k];
            if (k >= o) v += sb[pp][k - o];
            sb[np][k] = v;
        }
        __syncthreads();
        pp = np;
    }
    for (int k = t; k < 512; k += 256) {
        int ex = sb[pp][k] - lcnt[k];       // exclusive scan
        lstart[k] = ex;
        if (k < M) { deg[node0 + k] = lcnt[k]; start[node0 + k] = base + ex; }
    }
    __syncthreads();
    lcnt[t] = 0; lcnt[t + 256] = 0;
    __syncthreads();
    for (int i = t; i < cnt; i += 256) {
        int p = part[base + i];
        int nl = p & 511;
        int r = atomicAdd(&lcnt[nl], 1);
        csr[base + lstart[nl] + r] = p >> 9;  // window stays in one XCD's L2
    }
}

// ---- epilogue helpers (value args -> stays in registers, rule #20) ----
__device__ __forceinline__ void item_store(int n, int dg, const float* __restrict__ iemb,
                                           u16* __restrict__ rec, int l8,
                                           const float* __restrict__ s) {
    float dgf = (float)dg;
    float inv = 1.0f / fmaxf(dgf, 1.0f);
    float sw  = 1.0f - dgf / (dgf + 1e-8f);
    float4 e0 = ((const float4*)(iemb + n * 64))[l8 * 2];
    float4 e1 = ((const float4*)(iemb + n * 64))[l8 * 2 + 1];
    uint4 o;
    o.x = (unsigned)f2bf(sw * e0.x + s[0] * inv) | ((unsigned)f2bf(sw * e0.y + s[1] * inv) << 16);
    o.y = (unsigned)f2bf(sw * e0.z + s[2] * inv) | ((unsigned)f2bf(sw * e0.w + s[3] * inv) << 16);
    o.z = (unsigned)f2bf(sw * e1.x + s[4] * inv) | ((unsigned)f2bf(sw * e1.y + s[5] * inv) << 16);
    o.w = (unsigned)f2bf(sw * e1.z + s[6] * inv) | ((unsigned)f2bf(sw * e1.w + s[7] * inv) << 16);
    ((uint4*)(rec + n * 128 + 64))[l8] = o;          // hi half of record
}
__device__ __forceinline__ void soc_store(int n, int dg, unsigned* __restrict__ soc1, int l8,
                                          const float* __restrict__ s) {
    float inv = 1.0f / fmaxf((float)dg, 1.0f);
    uint4 o;
    o.x = (unsigned)f2bf(s[0] * inv) | ((unsigned)f2bf(s[1] * inv) << 16);
    o.y = (unsigned)f2bf(s[2] * inv) | ((unsigned)f2bf(s[3] * inv) << 16);
    o.z = (unsigned)f2bf(s[4] * inv) | ((unsigned)f2bf(s[5] * inv) << 16);
    o.w = (unsigned)f2bf(s[6] * inv) | ((unsigned)f2bf(s[7] * inv) << 16);
    ((uint4*)(soc1 + n * 32))[l8] = o;
}

// ---- core: gather-mean of two bf16 rowsets. dwordx4 row gathers (8 lanes per
//      128-B row -> one load inst = 1KB = 8 rows), UNCONDITIONAL clamped loads
//      so the compiler clusters 4x1KB in flight; butterfly-reduce across the
//      8 lane-groups at the end. (Pair = measured-best MLP; quad regressed.) ----
__device__ __forceinline__ void gather_pair(const unsigned* __restrict__ uh32,
                                            const int* __restrict__ csr,
                                            int jA, int dA, int jB, int dB,
                                            int lane, int g, int l8,
                                            float* __restrict__ aA,
                                            float* __restrict__ aB) {
    int cA = (lane < dA) ? csr[jA + lane] : 0;
    int cB = (lane < dB) ? csr[jB + lane] : 0;
    int kmA = dA < 64 ? dA : 64;
    int kmB = dB < 64 ? dB : 64;
    int clA = kmA > 0 ? kmA - 1 : 0;
    int clB = kmB > 0 ? kmB - 1 : 0;
    int km  = kmA > kmB ? kmA : kmB;
    for (int k = 0; k < km; k += 16) {
        int q0 = k + g, q1 = k + 8 + g;
        int iA0 = q0 < kmA ? q0 : clA;
        int iA1 = q1 < kmA ? q1 : clA;
        int iB0 = q0 < kmB ? q0 : clB;
        int iB1 = q1 < kmB ? q1 : clB;
        int rA0 = __shfl(cA, iA0), rA1 = __shfl(cA, iA1);
        int rB0 = __shfl(cB, iB0), rB1 = __shfl(cB, iB1);
        uint4 wA0 = *(const uint4*)(uh32 + rA0 * 32 + l8 * 4);
        uint4 wA1 = *(const uint4*)(uh32 + rA1 * 32 + l8 * 4);
        uint4 wB0 = *(const uint4*)(uh32 + rB0 * 32 + l8 * 4);
        uint4 wB1 = *(const uint4*)(uh32 + rB1 * 32 + l8 * 4);
        if (q0 < kmA) acc8(wA0, aA);
        if (q1 < kmA) acc8(wA1, aA);
        if (q0 < kmB) acc8(wB0, aB);
        if (q1 < kmB) acc8(wB1, aB);
    }
    for (int k = 64; k < dA; k += 8) {        // deg>64 tail (rare)
        int q = k + g; int idx = q < dA ? q : dA - 1;
        int r = csr[jA + idx];
        uint4 w = *(const uint4*)(uh32 + r * 32 + l8 * 4);
        if (q < dA) acc8(w, aA);
    }
    for (int k = 64; k < dB; k += 8) {
        int q = k + g; int idx = q < dB ? q : dB - 1;
        int r = csr[jB + idx];
        uint4 w = *(const uint4*)(uh32 + r * 32 + l8 * 4);
        if (q < dB) acc8(w, aB);
    }
    #pragma unroll
    for (int off = 8; off <= 32; off <<= 1) {
        #pragma unroll
        for (int m = 0; m < 8; ++m) {
            aA[m] += __shfl_xor(aA[m], off);
            aB[m] += __shfl_xor(aB[m], off);
        }
    }
}

// ---- fused gather: items (rec hi-half) and social users (soc1), TWO nodes
//      per wave (measured-best configuration) ----
__global__ void k_gather_fused(const float* __restrict__ iemb,
                               const unsigned* __restrict__ uh32,
                               const int* __restrict__ csrli, const int* __restrict__ istart,
                               const int* __restrict__ ideg, u16* __restrict__ rec,
                               const int* __restrict__ csrsd, const int* __restrict__ sstart,
                               const int* __restrict__ sdeg,
                               const unsigned char* __restrict__ needed,
                               unsigned* __restrict__ soc1) {
    int lane = threadIdx.x & 63;
    int wid  = blockIdx.x * 4 + (threadIdx.x >> 6);
    int nw   = gridDim.x * 4;
    int g = lane >> 3, l8 = lane & 7;
    const int NPI = NITEMS / 2;               // 25000 item pairs
    const int NP  = NPI + NUSERS / 2;         // + 50000 soc pairs
    for (int w = wid; w < NP; w += nw) {
        if (w < NPI) {
            int nA = w * 2, nB = nA + 1;
            int jA = istart[nA], dA = ideg[nA];
            int jB = istart[nB], dB = ideg[nB];
            float aA[8] = {0.f,0.f,0.f,0.f,0.f,0.f,0.f,0.f};
            float aB[8] = {0.f,0.f,0.f,0.f,0.f,0.f,0.f,0.f};
            gather_pair(uh32, csrli, jA, dA, jB, dB, lane, g, l8, aA, aB);
            if (g == 0)      item_store(nA, dA, iemb, rec, l8, aA);
            else if (g == 1) item_store(nB, dB, iemb, rec, l8, aB);
        } else {
            int nA = (w - NPI) * 2, nB = nA + 1;
            unsigned short nd = *(const unsigned short*)(needed + nA);   // nA even
            if (!nd) continue;                // neither row ever read
            int needA = nd & 0xff, needB = nd >> 8;
            int jA = sstart[nA], dA = needA ? sdeg[nA] : 0;
            int jB = sstart[nB], dB = needB ? sdeg[nB] : 0;
            float aA[8] = {0.f,0.f,0.f,0.f,0.f,0.f,0.f,0.f};
            float aB[8] = {0.f,0.f,0.f,0.f,0.f,0.f,0.f,0.f};
            gather_pair(uh32, csrsd, jA, dA, jB, dB, lane, g, l8, aA, aB);
            if (g == 0 && needA)      soc_store(nA, dA, soc1, l8, aA);
            else if (g == 1 && needB) soc_store(nB, dB, soc1, l8, aB);
        }
    }
}

// ---- fused epilogue: TWO batch elements per wave, interleaved.
//      Rating means read the item record (iembh|ri1 adjacent lines);
//      ru1/ru2 stay f32 in registers. ----
__global__ void k_final2(const int* __restrict__ users, const int* __restrict__ items,
                         const float* __restrict__ uemb, const float* __restrict__ iemb,
                         const u16* __restrict__ rec, const int* __restrict__ csrlu,
                         const int* __restrict__ ustart, const int* __restrict__ udeg,
                         const u16* __restrict__ soc1, const int* __restrict__ csrsd,
                         const int* __restrict__ sstart, const int* __restrict__ sdeg,
                         float* __restrict__ out) {
    int d   = threadIdx.x & 63;
    int wid = blockIdx.x * 4 + (threadIdx.x >> 6);
    if (wid >= NBATCH / 2) return;
    int bA = wid, bB = wid + NBATCH / 2;
    int uA = users[bA], uB = users[bB];
    int itA = items[bA], itB = items[bB];
    int juA = ustart[uA], duA = udeg[uA];
    int juB = ustart[uB], duB = udeg[uB];
    int jsA = sstart[uA], dsA = sdeg[uA];
    int jsB = sstart[uB], dsB = sdeg[uB];
    int cvUA = (d < duA) ? csrlu[juA + d] : 0;
    int cvUB = (d < duB) ? csrlu[juB + d] : 0;
    int cvSA = (d < dsA) ? csrsd[jsA + d] : 0;
    int cvSB = (d < dsB) ? csrsd[jsB + d] : 0;
    // ---- rating means over like-lists (both elements interleaved) ----
    int kmuA = duA < 64 ? duA : 64, cluA = kmuA > 0 ? kmuA - 1 : 0;
    int kmuB = duB < 64 ? duB : 64, cluB = kmuB > 0 ? kmuB - 1 : 0;
    int kmu = kmuA > kmuB ? kmuA : kmuB;
    float pA0=0.f,pA1=0.f,pA2=0.f,pA3=0.f, qA0=0.f,qA1=0.f,qA2=0.f,qA3=0.f;
    float pB0=0.f,pB1=0.f,pB2=0.f,pB3=0.f, qB0=0.f,qB1=0.f,qB2=0.f,qB3=0.f;
    for (int k = 0; k < kmu; k += 4) {
        int xA0 = k   < kmuA ? k   : cluA, xA1 = k+1 < kmuA ? k+1 : cluA;
        int xA2 = k+2 < kmuA ? k+2 : cluA, xA3 = k+3 < kmuA ? k+3 : cluA;
        int xB0 = k   < kmuB ? k   : cluB, xB1 = k+1 < kmuB ? k+1 : cluB;
        int xB2 = k+2 < kmuB ? k+2 : cluB, xB3 = k+3 < kmuB ? k+3 : cluB;
        int iA0 = __shfl(cvUA, xA0), iA1 = __shfl(cvUA, xA1);
        int iA2 = __shfl(cvUA, xA2), iA3 = __shfl(cvUA, xA3);
        int iB0 = __shfl(cvUB, xB0), iB1 = __shfl(cvUB, xB1);
        int iB2 = __shfl(cvUB, xB2), iB3 = __shfl(cvUB, xB3);
        float tA0 = bf2f(rec[iA0*128 + d]),      tA1 = bf2f(rec[iA1*128 + d]);
        float tA2 = bf2f(rec[iA2*128 + d]),      tA3 = bf2f(rec[iA3*128 + d]);
        float rA0 = bf2f(rec[iA0*128 + 64 + d]), rA1 = bf2f(rec[iA1*128 + 64 + d]);
        float rA2 = bf2f(rec[iA2*128 + 64 + d]), rA3 = bf2f(rec[iA3*128 + 64 + d]);
        float tB0 = bf2f(rec[iB0*128 + d]),      tB1 = bf2f(rec[iB1*128 + d]);
        float tB2 = bf2f(rec[iB2*128 + d]),      tB3 = bf2f(rec[iB3*128 + d]);
        float rB0 = bf2f(rec[iB0*128 + 64 + d]), rB1 = bf2f(rec[iB1*128 + 64 + d]);
        float rB2 = bf2f(rec[iB2*128 + 64 + d]), rB3 = bf2f(rec[iB3*128 + 64 + d]);
        if (k   < kmuA) { pA0 += tA0; qA0 += rA0; }
        if (k+1 < kmuA) { pA1 += tA1; qA1 += rA1; }
        if (k+2 < kmuA) { pA2 += tA2; qA2 += rA2; }
        if (k+3 < kmuA) { pA3 += tA3; qA3 += rA3; }
        if (k   < kmuB) { pB0 += tB0; qB0 += rB0; }
        if (k+1 < kmuB) { pB1 += tB1; qB1 += rB1; }
        if (k+2 < kmuB) { pB2 += tB2; qB2 += rB2; }
        if (k+3 < kmuB) { pB3 += tB3; qB3 += rB3; }
    }
    for (int j = juA + 64; j < juA + duA; ++j) {      // deg>64 tail (rare)
        int i0 = csrlu[j];
        pA0 += bf2f(rec[i0*128 + d]); qA0 += bf2f(rec[i0*128 + 64 + d]);
    }
    for (int j = juB + 64; j < juB + duB; ++j) {
        int i0 = csrlu[j];
        pB0 += bf2f(rec[i0*128 + d]); qB0 += bf2f(rec[i0*128 + 64 + d]);
    }
    // ---- social means over in-lists (both elements interleaved) ----
    int kmsA = dsA < 64 ? dsA : 64, clsA = kmsA > 0 ? kmsA - 1 : 0;
    int kmsB = dsB < 64 ? dsB : 64, clsB = kmsB > 0 ? kmsB - 1 : 0;
    int kms = kmsA > kmsB ? kmsA : kmsB;
    float sA0=0.f,sA1=0.f,sA2=0.f,sA3=0.f, sB0=0.f,sB1=0.f,sB2=0.f,sB3=0.f;
    for (int k = 0; k < kms; k += 4) {
        int xA0 = k   < kmsA ? k   : clsA, xA1 = k+1 < kmsA ? k+1 : clsA;
        int xA2 = k+2 < kmsA ? k+2 : clsA, xA3 = k+3 < kmsA ? k+3 : clsA;
        int xB0 = k   < kmsB ? k   : clsB, xB1 = k+1 < kmsB ? k+1 : clsB;
        int xB2 = k+2 < kmsB ? k+2 : clsB, xB3 = k+3 < kmsB ? k+3 : clsB;
        int cA0 = __shfl(cvSA, xA0), cA1 = __shfl(cvSA, xA1);
        int cA2 = __shfl(cvSA, xA2), cA3 = __shfl(cvSA, xA3);
        int cB0 = __shfl(cvSB, xB0), cB1 = __shfl(cvSB, xB1);
        int cB2 = __shfl(cvSB, xB2), cB3 = __shfl(cvSB, xB3);
        float fA0 = bf2f(soc1[cA0*64 + d]), fA1 = bf2f(soc1[cA1*64 + d]);
        float fA2 = bf2f(soc1[cA2*64 + d]), fA3 = bf2f(soc1[cA3*64 + d]);
        float fB0 = bf2f(soc1[cB0*64 + d]), fB1 = bf2f(soc1[cB1*64 + d]);
        float fB2 = bf2f(soc1[cB2*64 + d]), fB3 = bf2f(soc1[cB3*64 + d]);
        if (k   < kmsA) sA0 += fA0;
        if (k+1 < kmsA) sA1 += fA1;
        if (k+2 < kmsA) sA2 += fA2;
        if (k+3 < kmsA) sA3 += fA3;
        if (k   < kmsB) sB0 += fB0;
        if (k+1 < kmsB) sB1 += fB1;
        if (k+2 < kmsB) sB2 += fB2;
        if (k+3 < kmsB) sB3 += fB3;
    }
    for (int j = jsA + 64; j < jsA + dsA; ++j)        // deg>64 tail (rare)
        sA0 += bf2f(soc1[csrsd[j]*64 + d]);
    for (int j = jsB + 64; j < jsB + dsB; ++j)
        sB0 += bf2f(soc1[csrsd[j]*64 + d]);
    // ---- combine + write, element A ----
    {
        float invU = 1.0f / fmaxf((float)duA, 1.0f);
        float ru1 = ((pA0 + pA1) + (pA2 + pA3)) * invU;
        float ru2 = ((qA0 + qA1) + (qA2 + qA3)) * invU;
        float s2 = ((sA0 + sA1) + (sA2 + sA3)) / fmaxf((float)dsA, 1.0f);
        float ud = (float)duA;
        float usw = 1.0f - ud / (ud + 1e-8f);
        float ue = uemb[uA * 64 + d];
        float s1 = bf2f(soc1[uA * 64 + d]);
        float r1 = usw * ue + ru1;
        float r2 = usw * r1 + ru2;
        float fu = ue + 0.5f * (s1 + r1) + 0.5f * (s2 + r2);
        float iv = iemb[itA * 64 + d];
        out[NBATCH + bA * 64 + d]               = fu;
        out[NBATCH + NBATCH * 64 + bA * 64 + d] = iv;
        float p = fu * iv;
        #pragma unroll
        for (int o = 32; o > 0; o >>= 1) p += __shfl_down(p, o);
        if (d == 0) out[bA] = 1.0f / (1.0f + __expf(-p));
    }
    // ---- combine + write, element B ----
    {
        float invU = 1.0f / fmaxf((float)duB, 1.0f);
        float ru1 = ((pB0 + pB1) + (pB2 + pB3)) * invU;
        float ru2 = ((qB0 + qB1) + (qB2 + qB3)) * invU;
        float s2 = ((sB0 + sB1) + (sB2 + sB3)) / fmaxf((float)dsB, 1.0f);
        float ud = (float)duB;
        float usw = 1.0f - ud / (ud + 1e-8f);
        float ue = uemb[uB * 64 + d];
        float s1 = bf2f(soc1[uB * 64 + d]);
        float r1 = usw * ue + ru1;
        float r2 = usw * r1 + ru2;
        float fu = ue + 0.5f * (s1 + r1) + 0.5f * (s2 + r2);
        float iv = iemb[itB * 64 + d];
        out[NBATCH + bB * 64 + d]               = fu;
        out[NBATCH + NBATCH * 64 + bB * 64 + d] = iv;
        float p = fu * iv;
        #pragma unroll
        for (int o = 32; o > 0; o >>= 1) p += __shfl_down(p, o);
        if (d == 0) out[bB] = 1.0f / (1.0f + __expf(-p));
    }
}

extern "C" void kernel_launch(void* const* d_in, const int* in_sizes, int n_in,
                              void* d_out, int out_size, void* d_ws, size_t ws_size,
                              hipStream_t stream) {
    const float* uemb  = (const float*)d_in[0];
    const float* iemb  = (const float*)d_in[1];
    const int*   users = (const int*)d_in[2];
    const int*   items = (const int*)d_in[3];
    const int*   ssrc  = (const int*)d_in[4];
    const int*   sdst  = (const int*)d_in[5];
    const int*   lu    = (const int*)d_in[6];
    const int*   li    = (const int*)d_in[7];
    float* out = (float*)d_out;

    if (ws_size < (size_t)WS_FLOATS * 4) return;  // would show absmax==0.5 diagnostic

    int*           W      = (int*)d_ws;
    int*           gcnt   = W + OFF_GC;
    int*           gbase  = W + OFF_GB;
    int*           gcur   = W + OFF_GCUR;
    unsigned*      bits   = (unsigned*)(W + OFF_BITS);
    unsigned char* needed = (unsigned char*)(W + OFF_NEED);
    int*           ideg   = W + OFF_IDEG;
    int*           udeg   = W + OFF_UDEG;
    int*           sdeg   = W + OFF_SDEG;
    int*           istart = W + OFF_ISTART;
    int*           ustart = W + OFF_USTART;
    int*           sstart = W + OFF_SSTART;
    u16*           uembh  = (u16*)(W + OFF_UEMBH);
    u16*           rec    = (u16*)(W + OFF_REC);
    u16*           soc1   = (u16*)(W + OFF_SOC1);
    int*           partLI = W + OFF_PARTLI;
    int*           partLU = W + OFF_PARTLU;
    int*           partSD = W + OFF_PARTSD;
    int*           csrli  = W + OFF_CSRLI;
    int*           csrlu  = W + OFF_CSRLU;
    int*           csrsd  = W + OFF_CSRSD;

    hipMemsetAsync(d_ws, 0, (size_t)OFF_ZEND * 4, stream);   // gcnt + bits + needed

    const int B = 256;

    // batch membership (tiny; must precede passA's bitmask load)
    k_slot<<<(NBATCH + B - 1) / B, B, 0, stream>>>(users, bits, needed);

    // bf16 shadows overlapped with passA histograms (independent work, 1 dispatch)
    k_cvtA<<<NB_CVT + NBLK_E, B, 0, stream>>>(uemb, iemb, lu, li, sdst, ssrc,
                                              bits, gcnt, needed, uembh, rec);

    k_passB<<<1, B, 0, stream>>>(gcnt, gbase, gcur);
    k_passC<<<NBLK_E, B, 0, stream>>>(lu, li, sdst, ssrc, bits, gcur,
                                      partLI, partLU, partSD);
    k_passD<<<588, B, 0, stream>>>(gcnt, gbase, partLI, partLU, partSD,
                                   csrli, csrlu, csrsd, ideg, udeg, sdeg,
                                   istart, ustart, sstart);

    // fused item + social gathers (pair = measured-best MLP)
    k_gather_fused<<<GGRID, B, 0, stream>>>(iemb, (const unsigned*)uembh,
                                            csrli, istart, ideg, rec,
                                            csrsd, sstart, sdeg, needed,
                                            (unsigned*)soc1);

    // fused rating means + social mean + epilogue (2 elements per wave)
    k_final2<<<2048, B, 0, stream>>>(users, items, uemb, iemb, rec, csrlu,
                                     ustart, udeg, soc1, csrsd, sstart, sdeg, out);
}